// Round 1
// baseline (711.795 us; speedup 1.0000x reference)
//
#include <hip/hip_runtime.h>

#define NB 8
#define CH 256
#define CB 128
#define HSW 64
#define HSP (HSW*HSW)   // 4096
#define LW 128
#define LP (LW*LW)      // 16384

// ---- workspace layout (floats). Total ~55.7M floats = 223 MB ----
static constexpr size_t S_HS  = (size_t)NB*CB*HSP;
static constexpr size_t S_Q   = (size_t)NB*LP*CB;
static constexpr size_t S_KV1 = (size_t)NB*HSP*CB;

static constexpr size_t OFF_HS   = 0;
static constexpr size_t OFF_Q    = OFF_HS + S_HS;
static constexpr size_t OFF_K    = OFF_Q + S_Q;
static constexpr size_t OFF_V    = OFF_K + S_KV1;
static constexpr size_t OFF_MRL  = OFF_V + S_KV1;
static constexpr size_t OFF_MRH  = OFF_MRL + (size_t)NB*LP*2;
static constexpr size_t OFF_KM8  = OFF_MRH + (size_t)NB*HSP*2;
static constexpr size_t OFF_KV8  = OFF_KM8 + (size_t)1800*128;
static constexpr size_t OFF_KM16 = OFF_KV8 + (size_t)1800*4096;
static constexpr size_t OFF_KV16 = OFF_KM16 + (size_t)392*128;
static constexpr size_t OFF_ACC  = OFF_KV16 + (size_t)392*4096;

// ---------------- 1x1 conv: hs[b][o][pix] = sum_c high[b][c][pix]*cw[o][c] + cb[o] ----------------
__global__ __launch_bounds__(256)
void k_conv(const float* __restrict__ high, const float* __restrict__ cw,
            const float* __restrict__ cb, float* __restrict__ hs) {
  __shared__ __align__(16) float wl[64][36];
  int blk = blockIdx.x;
  int oh = blk & 3;
  int pt = (blk >> 2) & 15;
  int b  = blk >> 6;
  int obase = oh * 32;
  int pix = pt * 256 + threadIdx.x;
  const float* xin = high + (size_t)b * CH * HSP + pix;
  float acc[32];
  #pragma unroll
  for (int j = 0; j < 32; ++j) acc[j] = cb[obase + j];
  for (int c0 = 0; c0 < CH; c0 += 64) {
    __syncthreads();
    for (int e = threadIdx.x; e < 64*32; e += 256) {
      int cc = e & 63, j = e >> 6;
      wl[cc][j] = cw[(size_t)(obase + j) * CH + c0 + cc];
    }
    __syncthreads();
    #pragma unroll 4
    for (int cc = 0; cc < 64; ++cc) {
      float x = xin[(size_t)(c0 + cc) * HSP];
      #pragma unroll
      for (int j4 = 0; j4 < 8; ++j4) {
        float4 w = *(const float4*)&wl[cc][j4*4];
        acc[j4*4+0] += x * w.x;
        acc[j4*4+1] += x * w.y;
        acc[j4*4+2] += x * w.z;
        acc[j4*4+3] += x * w.w;
      }
    }
  }
  float* op = hs + ((size_t)b * CB + obase) * HSP + pix;
  #pragma unroll
  for (int j = 0; j < 32; ++j) op[(size_t)j * HSP] = acc[j];
}

// ---------------- per-pixel LayerNorm stats (mean, rstd) ----------------
__global__ __launch_bounds__(256)
void k_lnstats(const float* __restrict__ x, float* __restrict__ mr, int npix) {
  size_t idx = (size_t)blockIdx.x * 256 + threadIdx.x;
  int b = (int)(idx / (size_t)npix);
  int p = (int)(idx - (size_t)b * npix);
  const float* xp = x + (size_t)b * CB * npix + p;
  float s = 0.f, ss = 0.f;
  #pragma unroll 8
  for (int c = 0; c < CB; ++c) { float v = xp[(size_t)c * npix]; s += v; ss += v * v; }
  float m = s * (1.f / CB);
  float var = ss * (1.f / CB) - m * m;
  mr[2*idx]   = m;
  mr[2*idx+1] = rsqrtf(fmaxf(var, 0.f) + 1e-5f);
}

// ---------------- fused LN + linear (+ optional elu+1), pixel-major output ----------------
template<int ACT>
__global__ __launch_bounds__(256)
void k_proj(const float* __restrict__ x, const float* __restrict__ mr,
            const float* __restrict__ lng, const float* __restrict__ lnb,
            const float* __restrict__ W, const float* __restrict__ bias,
            float* __restrict__ y, int npix) {
  __shared__ __align__(16) float Al[32][68];    // [cc][p]
  __shared__ __align__(16) float Wl[32][132];   // [cc][o]
  __shared__ float ml[64], rl[64], gl[CB], bl[CB];
  int t = threadIdx.x;
  size_t pixbase = (size_t)blockIdx.x * 64;
  int b = (int)(pixbase / (size_t)npix);
  int prel = (int)(pixbase - (size_t)b * npix);
  const float* xb = x + (size_t)b * CB * npix + prel;
  if (t < 64) {
    size_t gi = pixbase + t;
    ml[t] = mr[2*gi]; rl[t] = mr[2*gi+1];
  }
  if (t >= 128) { gl[t-128] = lng[t-128]; bl[t-128] = lnb[t-128]; }
  int tx = t & 15, ty = t >> 4;
  float acc[4][8];
  #pragma unroll
  for (int i = 0; i < 4; ++i)
    #pragma unroll
    for (int j = 0; j < 8; ++j) acc[i][j] = 0.f;
  for (int c0 = 0; c0 < CB; c0 += 32) {
    __syncthreads();
    #pragma unroll
    for (int e = t; e < 2048; e += 256) {
      int p = e & 63, cc = e >> 6;
      float v = xb[(size_t)(c0+cc)*npix + p];
      Al[cc][p] = (v - ml[p]) * rl[p] * gl[c0+cc] + bl[c0+cc];
    }
    #pragma unroll
    for (int e = t; e < 4096; e += 256) {
      int cc = e & 31, o = e >> 5;
      Wl[cc][o] = W[(size_t)o*CB + c0 + cc];
    }
    __syncthreads();
    #pragma unroll 8
    for (int cc = 0; cc < 32; ++cc) {
      float4 a4 = *(const float4*)&Al[cc][ty*4];
      float4 w0 = *(const float4*)&Wl[cc][tx*8];
      float4 w1 = *(const float4*)&Wl[cc][tx*8+4];
      float av[4] = {a4.x, a4.y, a4.z, a4.w};
      float wv[8] = {w0.x,w0.y,w0.z,w0.w,w1.x,w1.y,w1.z,w1.w};
      #pragma unroll
      for (int i = 0; i < 4; ++i)
        #pragma unroll
        for (int j = 0; j < 8; ++j) acc[i][j] += av[i]*wv[j];
    }
  }
  float bv_[8];
  #pragma unroll
  for (int j = 0; j < 8; ++j) bv_[j] = bias[tx*8+j];
  #pragma unroll
  for (int i = 0; i < 4; ++i) {
    size_t prow = pixbase + ty*4 + i;
    float vv[8];
    #pragma unroll
    for (int j = 0; j < 8; ++j) {
      float v = acc[i][j] + bv_[j];
      if (ACT) v = (v > 0.f) ? v + 1.f : __expf(v);  // elu(v)+1
      vv[j] = v;
    }
    float* yp = y + prow*CB + tx*8;
    *(float4*)yp     = make_float4(vv[0],vv[1],vv[2],vv[3]);
    *(float4*)(yp+4) = make_float4(vv[4],vv[5],vv[6],vv[7]);
  }
}

// ---------------- per-window kmean + kv (32x32 per head) ----------------
template<int WS>
__global__ __launch_bounds__(256)
void k_winkv(const float* __restrict__ kall, const float* __restrict__ vall,
             float* __restrict__ km, float* __restrict__ kv) {
  constexpr int NWIN = (HSW - WS)/(WS/2) + 1;
  constexpr int NK = WS*WS;
  __shared__ __align__(16) float kl[32][128];
  __shared__ __align__(16) float vl[32][128];
  int w = blockIdx.x;
  int b = w / (NWIN*NWIN);
  int rem = w - b*(NWIN*NWIN);
  int wi = rem / NWIN, wj = rem - (rem/NWIN)*NWIN;
  int y0 = wi*(WS/2), x0 = wj*(WS/2);
  int t = threadIdx.x;
  int h = t >> 6, d = (t>>1)&31, ep = t&1, e0 = ep*16;
  float acc[16];
  #pragma unroll
  for (int k2 = 0; k2 < 16; ++k2) acc[k2] = 0.f;
  float ksum = 0.f;
  for (int n0 = 0; n0 < NK; n0 += 32) {
    __syncthreads();
    #pragma unroll
    for (int e = t; e < 4096; e += 256) {
      int c = e & 127, rr = e >> 7;
      int n = n0 + rr;
      int py = y0 + n / WS, px = x0 + (n - (n/WS)*WS);
      size_t pix = (size_t)b*HSP + (size_t)py*HSW + px;
      kl[rr][c] = kall[pix*CB + c];
      vl[rr][c] = vall[pix*CB + c];
    }
    __syncthreads();
    #pragma unroll 4
    for (int rr = 0; rr < 32; ++rr) {
      float kd = kl[rr][h*32+d];
      ksum += kd;
      #pragma unroll
      for (int k4 = 0; k4 < 4; ++k4) {
        float4 v4 = *(const float4*)&vl[rr][h*32+e0+k4*4];
        acc[k4*4+0] += kd*v4.x;
        acc[k4*4+1] += kd*v4.y;
        acc[k4*4+2] += kd*v4.z;
        acc[k4*4+3] += kd*v4.w;
      }
    }
  }
  float* kvp = kv + (size_t)w*4096 + h*1024 + d*32 + e0;
  #pragma unroll
  for (int k2 = 0; k2 < 16; ++k2) kvp[k2] = acc[k2] * (1.f/WS);
  if (ep == 0) km[(size_t)w*128 + h*32 + d] = ksum * (1.f/NK);
}

// ---------------- gather-fold: acc[pix][c] = sum over covering windows of ww*z*(q@kv) ----------------
__global__ __launch_bounds__(256)
void k_fold(const float* __restrict__ qall,
            const float* __restrict__ km8, const float* __restrict__ kv8,
            const float* __restrict__ km16, const float* __restrict__ kv16,
            const float* __restrict__ wwt,
            float* __restrict__ accimg) {
  __shared__ __align__(16) float ql[64][132];   // permuted: ql[p][d*4+h] = q[p][h*32+d]
  __shared__ __align__(16) float kvl[4][1032];  // [h][d*32+e], h-stride 1032 de-conflicts banks
  __shared__ float kml[4][33];
  int bid = blockIdx.x;
  int b = bid >> 8;
  int tile = bid & 255;
  int tyi = tile >> 4, txi = tile & 15;
  int y0 = tyi*8, x0 = txi*8;
  int t = threadIdx.x;
  int p = t >> 2, h = t & 3;
  size_t qbase = ((size_t)b*LP + (size_t)y0*LW + x0);
  for (int e = t; e < 8192; e += 256) {
    int c = e & 127, pp = e >> 7;
    float v = qall[(qbase + (size_t)(pp>>3)*LW + (pp&7))*CB + c];
    ql[pp][(c&31)*4 + (c>>5)] = v;
  }
  float acc[32];
  #pragma unroll
  for (int k2 = 0; k2 < 32; ++k2) acc[k2] = 0.f;
  float wwv0 = wwt[0], wwv1 = wwt[1];
  for (int wsi = 0; wsi < 2; ++wsi) {
    const int ws = wsi ? 16 : 8;
    const int n  = wsi ? 7 : 15;
    const float wwv = wsi ? wwv1 : wwv0;
    const float* kms = wsi ? km16 : km8;
    const float* kvs = wsi ? kv16 : kv8;
    int ry = y0 / ws, rx = x0 / ws;
    for (int ia = 0; ia < 2; ++ia) {
      for (int ja = 0; ja < 2; ++ja) {
        int ar = ry - 1 + ia, ac = rx - 1 + ja;
        if (ar < 0 || ar >= n || ac < 0 || ac >= n) continue;  // block-uniform
        size_t w = ((size_t)b*n + ar)*n + ac;
        __syncthreads();
        if (t < 128) kml[t>>5][t&31] = kms[w*128 + t];
        #pragma unroll
        for (int e = t; e < 4096; e += 256) kvl[e>>10][e&1023] = kvs[w*4096 + e];
        __syncthreads();
        float zd = 0.f;
        #pragma unroll
        for (int d = 0; d < 32; ++d) zd += ql[p][d*4+h] * kml[h][d];
        float f = wwv / (zd + 1e-6f);
        #pragma unroll 2
        for (int d = 0; d < 32; ++d) {
          float fq = f * ql[p][d*4+h];
          const float* kvrow = &kvl[h][d*32];
          #pragma unroll
          for (int e4 = 0; e4 < 8; ++e4) {
            float4 v4 = *(const float4*)&kvrow[e4*4];
            acc[e4*4+0] += fq*v4.x;
            acc[e4*4+1] += fq*v4.y;
            acc[e4*4+2] += fq*v4.z;
            acc[e4*4+3] += fq*v4.w;
          }
        }
      }
    }
  }
  size_t pix = (size_t)b*LP + (size_t)(y0 + (p>>3))*LW + (x0 + (p&7));
  float* op = accimg + pix*CB + h*32;
  #pragma unroll
  for (int e4 = 0; e4 < 8; ++e4)
    *(float4*)&op[e4*4] = make_float4(acc[e4*4],acc[e4*4+1],acc[e4*4+2],acc[e4*4+3]);
}

// ---------------- final: out = 0.5*(acc@wo.T + bo*mult); final = a*out + (1-a)*low ----------------
__global__ __launch_bounds__(256)
void k_final(const float* __restrict__ accimg, const float* __restrict__ wo,
             const float* __restrict__ bo, const float* __restrict__ low,
             const float* __restrict__ alpha,
             float* __restrict__ out0, float* __restrict__ out1) {
  __shared__ __align__(16) float Al[32][68];
  __shared__ __align__(16) float Wl[32][132];
  int t = threadIdx.x;
  size_t pixbase = (size_t)blockIdx.x * 64;
  int b = (int)(pixbase / LP);
  int prel = (int)(pixbase - (size_t)b * LP);
  int py = prel >> 7;
  int px0 = prel & 127;
  int tx = t & 15, ty = t >> 4;
  float acc[4][8];
  #pragma unroll
  for (int i = 0; i < 4; ++i)
    #pragma unroll
    for (int j = 0; j < 8; ++j) acc[i][j] = 0.f;
  for (int c0 = 0; c0 < CB; c0 += 32) {
    __syncthreads();
    #pragma unroll
    for (int e = t; e < 2048; e += 256) {
      int cc = e & 31, pp = e >> 5;
      Al[cc][pp] = accimg[(pixbase + pp)*CB + c0 + cc];
    }
    #pragma unroll
    for (int e = t; e < 4096; e += 256) {
      int cc = e & 31, o = e >> 5;
      Wl[cc][o] = wo[(size_t)o*CB + c0 + cc];
    }
    __syncthreads();
    #pragma unroll 8
    for (int cc = 0; cc < 32; ++cc) {
      float4 a4 = *(const float4*)&Al[cc][ty*4];
      float4 w0 = *(const float4*)&Wl[cc][tx*8];
      float4 w1 = *(const float4*)&Wl[cc][tx*8+4];
      float av[4] = {a4.x, a4.y, a4.z, a4.w};
      float wv[8] = {w0.x,w0.y,w0.z,w0.w,w1.x,w1.y,w1.z,w1.w};
      #pragma unroll
      for (int i = 0; i < 4; ++i)
        #pragma unroll
        for (int j = 0; j < 8; ++j) acc[i][j] += av[i]*wv[j];
    }
  }
  int cy8  = (py >= 8)  + (py <= 119);
  int cy16 = (py >= 16) + (py <= 111);
  float a = alpha[0];
  float multv[4];
  #pragma unroll
  for (int i = 0; i < 4; ++i) {
    int px = px0 + ty*4 + i;
    int cx8  = (px >= 8)  + (px <= 119);
    int cx16 = (px >= 16) + (px <= 111);
    multv[i] = (float)(cy8*cx8 + cy16*cx16);
  }
  #pragma unroll
  for (int j = 0; j < 8; ++j) {
    int o = tx*8 + j;
    float bov = bo[o];
    size_t addr = ((size_t)b*CB + o)*LP + prel + ty*4;
    float4 lw = *(const float4*)(low + addr);
    float g0 = 0.5f*(acc[0][j] + bov*multv[0]);
    float g1 = 0.5f*(acc[1][j] + bov*multv[1]);
    float g2 = 0.5f*(acc[2][j] + bov*multv[2]);
    float g3 = 0.5f*(acc[3][j] + bov*multv[3]);
    *(float4*)(out0 + addr) = make_float4(g0,g1,g2,g3);
    *(float4*)(out1 + addr) = make_float4(a*g0 + (1.f-a)*lw.x,
                                          a*g1 + (1.f-a)*lw.y,
                                          a*g2 + (1.f-a)*lw.z,
                                          a*g3 + (1.f-a)*lw.w);
  }
}

extern "C" void kernel_launch(void* const* d_in, const int* in_sizes, int n_in,
                              void* d_out, int out_size, void* d_ws, size_t ws_size,
                              hipStream_t stream) {
  const float* high  = (const float*)d_in[0];
  const float* low   = (const float*)d_in[1];
  const float* cw    = (const float*)d_in[2];
  const float* cb    = (const float*)d_in[3];
  const float* lng   = (const float*)d_in[4];
  const float* lnb   = (const float*)d_in[5];
  const float* wq    = (const float*)d_in[6];
  const float* bq    = (const float*)d_in[7];
  const float* wk    = (const float*)d_in[8];
  const float* bk    = (const float*)d_in[9];
  const float* wv    = (const float*)d_in[10];
  const float* bv    = (const float*)d_in[11];
  const float* wo    = (const float*)d_in[12];
  const float* bo    = (const float*)d_in[13];
  const float* wwt   = (const float*)d_in[14];
  const float* alpha = (const float*)d_in[15];

  float* ws   = (float*)d_ws;
  float* hs   = ws + OFF_HS;
  float* qall = ws + OFF_Q;
  float* kall = ws + OFF_K;
  float* vall = ws + OFF_V;
  float* mrl  = ws + OFF_MRL;
  float* mrh  = ws + OFF_MRH;
  float* km8  = ws + OFF_KM8;
  float* kv8  = ws + OFF_KV8;
  float* km16 = ws + OFF_KM16;
  float* kv16 = ws + OFF_KV16;
  float* accimg = ws + OFF_ACC;

  float* out0 = (float*)d_out;
  float* out1 = out0 + (size_t)NB*CB*LP;

  k_conv<<<512, 256, 0, stream>>>(high, cw, cb, hs);
  k_lnstats<<<512, 256, 0, stream>>>(low, mrl, LP);
  k_lnstats<<<128, 256, 0, stream>>>(hs, mrh, HSP);
  k_proj<1><<<2048, 256, 0, stream>>>(low, mrl, lng, lnb, wq, bq, qall, LP);
  k_proj<1><<<512, 256, 0, stream>>>(hs, mrh, lng, lnb, wk, bk, kall, HSP);
  k_proj<0><<<512, 256, 0, stream>>>(hs, mrh, lng, lnb, wv, bv, vall, HSP);
  k_winkv<8><<<1800, 256, 0, stream>>>(kall, vall, km8, kv8);
  k_winkv<16><<<392, 256, 0, stream>>>(kall, vall, km16, kv16);
  k_fold<<<2048, 256, 0, stream>>>(qall, km8, kv8, km16, kv16, wwt, accimg);
  k_final<<<2048, 256, 0, stream>>>(accimg, wo, bo, low, alpha, out0, out1);
}

// Round 2
// 544.024 us; speedup vs baseline: 1.3084x; 1.3084x over previous
//
#include <hip/hip_runtime.h>

#define NB 8
#define CH 256
#define CB 128
#define HSW 64
#define HSP (HSW*HSW)   // 4096
#define LW 128
#define LP (LW*LW)      // 16384

typedef __attribute__((ext_vector_type(8))) short bf16x8;
typedef __attribute__((ext_vector_type(4))) float f32x4;

__device__ inline ushort f2bf(float x) {
  uint u = __float_as_uint(x);
  uint r = (u + 0x7fffu + ((u >> 16) & 1u)) >> 16;
  return (ushort)r;
}

// ---- workspace layout (float units) ----
static constexpr size_t S_HS  = (size_t)NB*CB*HSP;      // 4194304
static constexpr size_t S_Q   = (size_t)NB*LP*CB;       // 16777216 (ushort count; /2 floats)
static constexpr size_t S_KV1 = (size_t)NB*HSP*CB;      // 4194304

static constexpr size_t OFF_HS    = 0;
static constexpr size_t OFF_QBF   = OFF_HS + S_HS;            // bf16 q, S_Q ushorts
static constexpr size_t OFF_K     = OFF_QBF + S_Q/2;
static constexpr size_t OFF_V     = OFF_K + S_KV1;
static constexpr size_t OFF_MRL   = OFF_V + S_KV1;
static constexpr size_t OFF_MRH   = OFF_MRL + (size_t)NB*LP*2;
static constexpr size_t OFF_KM8   = OFF_MRH + (size_t)NB*HSP*2;
static constexpr size_t OFF_KV8T  = OFF_KM8 + (size_t)1800*128;     // bf16 kvT, 1800*4096 ushorts
static constexpr size_t OFF_KM16  = OFF_KV8T + (size_t)1800*4096/2;
static constexpr size_t OFF_KV16T = OFF_KM16 + (size_t)392*128;     // bf16 kvT, 392*4096 ushorts
static constexpr size_t OFF_ACC   = OFF_KV16T + (size_t)392*4096/2;

// ---------------- 1x1 conv ----------------
__global__ __launch_bounds__(256)
void k_conv(const float* __restrict__ high, const float* __restrict__ cw,
            const float* __restrict__ cb, float* __restrict__ hs) {
  __shared__ __align__(16) float wl[64][36];
  int blk = blockIdx.x;
  int oh = blk & 3;
  int pt = (blk >> 2) & 15;
  int b  = blk >> 6;
  int obase = oh * 32;
  int pix = pt * 256 + threadIdx.x;
  const float* xin = high + (size_t)b * CH * HSP + pix;
  float acc[32];
  #pragma unroll
  for (int j = 0; j < 32; ++j) acc[j] = cb[obase + j];
  for (int c0 = 0; c0 < CH; c0 += 64) {
    __syncthreads();
    for (int e = threadIdx.x; e < 64*32; e += 256) {
      int cc = e & 63, j = e >> 6;
      wl[cc][j] = cw[(size_t)(obase + j) * CH + c0 + cc];
    }
    __syncthreads();
    #pragma unroll 4
    for (int cc = 0; cc < 64; ++cc) {
      float x = xin[(size_t)(c0 + cc) * HSP];
      #pragma unroll
      for (int j4 = 0; j4 < 8; ++j4) {
        float4 w = *(const float4*)&wl[cc][j4*4];
        acc[j4*4+0] += x * w.x;
        acc[j4*4+1] += x * w.y;
        acc[j4*4+2] += x * w.z;
        acc[j4*4+3] += x * w.w;
      }
    }
  }
  float* op = hs + ((size_t)b * CB + obase) * HSP + pix;
  #pragma unroll
  for (int j = 0; j < 32; ++j) op[(size_t)j * HSP] = acc[j];
}

// ---------------- per-pixel LayerNorm stats ----------------
__global__ __launch_bounds__(256)
void k_lnstats(const float* __restrict__ x, float* __restrict__ mr, int npix) {
  size_t idx = (size_t)blockIdx.x * 256 + threadIdx.x;
  int b = (int)(idx / (size_t)npix);
  int p = (int)(idx - (size_t)b * npix);
  const float* xp = x + (size_t)b * CB * npix + p;
  float s = 0.f, ss = 0.f;
  #pragma unroll 8
  for (int c = 0; c < CB; ++c) { float v = xp[(size_t)c * npix]; s += v; ss += v * v; }
  float m = s * (1.f / CB);
  float var = ss * (1.f / CB) - m * m;
  mr[2*idx]   = m;
  mr[2*idx+1] = rsqrtf(fmaxf(var, 0.f) + 1e-5f);
}

// ---------------- fused LN + linear (+ optional elu+1), pixel-major out, f32 or bf16 ----------------
template<int ACT, int BF>
__global__ __launch_bounds__(256)
void k_proj(const float* __restrict__ x, const float* __restrict__ mr,
            const float* __restrict__ lng, const float* __restrict__ lnb,
            const float* __restrict__ W, const float* __restrict__ bias,
            void* __restrict__ yv, int npix) {
  __shared__ __align__(16) float Al[32][68];
  __shared__ __align__(16) float Wl[32][132];
  __shared__ float ml[64], rl[64], gl[CB], bl[CB];
  int t = threadIdx.x;
  size_t pixbase = (size_t)blockIdx.x * 64;
  int b = (int)(pixbase / (size_t)npix);
  int prel = (int)(pixbase - (size_t)b * npix);
  const float* xb = x + (size_t)b * CB * npix + prel;
  if (t < 64) {
    size_t gi = pixbase + t;
    ml[t] = mr[2*gi]; rl[t] = mr[2*gi+1];
  }
  if (t >= 128) { gl[t-128] = lng[t-128]; bl[t-128] = lnb[t-128]; }
  int tx = t & 15, ty = t >> 4;
  float acc[4][8];
  #pragma unroll
  for (int i = 0; i < 4; ++i)
    #pragma unroll
    for (int j = 0; j < 8; ++j) acc[i][j] = 0.f;
  for (int c0 = 0; c0 < CB; c0 += 32) {
    __syncthreads();
    #pragma unroll
    for (int e = t; e < 2048; e += 256) {
      int p = e & 63, cc = e >> 6;
      float v = xb[(size_t)(c0+cc)*npix + p];
      Al[cc][p] = (v - ml[p]) * rl[p] * gl[c0+cc] + bl[c0+cc];
    }
    #pragma unroll
    for (int e = t; e < 4096; e += 256) {
      int cc = e & 31, o = e >> 5;
      Wl[cc][o] = W[(size_t)o*CB + c0 + cc];
    }
    __syncthreads();
    #pragma unroll 8
    for (int cc = 0; cc < 32; ++cc) {
      float4 a4 = *(const float4*)&Al[cc][ty*4];
      float4 w0 = *(const float4*)&Wl[cc][tx*8];
      float4 w1 = *(const float4*)&Wl[cc][tx*8+4];
      float av[4] = {a4.x, a4.y, a4.z, a4.w};
      float wv[8] = {w0.x,w0.y,w0.z,w0.w,w1.x,w1.y,w1.z,w1.w};
      #pragma unroll
      for (int i = 0; i < 4; ++i)
        #pragma unroll
        for (int j = 0; j < 8; ++j) acc[i][j] += av[i]*wv[j];
    }
  }
  float bv_[8];
  #pragma unroll
  for (int j = 0; j < 8; ++j) bv_[j] = bias[tx*8+j];
  #pragma unroll
  for (int i = 0; i < 4; ++i) {
    size_t prow = pixbase + ty*4 + i;
    float vv[8];
    #pragma unroll
    for (int j = 0; j < 8; ++j) {
      float v = acc[i][j] + bv_[j];
      if (ACT) v = (v > 0.f) ? v + 1.f : __expf(v);  // elu(v)+1
      vv[j] = v;
    }
    if (BF) {
      bf16x8 pk;
      #pragma unroll
      for (int j = 0; j < 8; ++j) pk[j] = (short)f2bf(vv[j]);
      *((bf16x8*)((ushort*)yv + prow*CB + tx*8)) = pk;
    } else {
      float* yp = (float*)yv + prow*CB + tx*8;
      *(float4*)yp     = make_float4(vv[0],vv[1],vv[2],vv[3]);
      *(float4*)(yp+4) = make_float4(vv[4],vv[5],vv[6],vv[7]);
    }
  }
}

// ---------------- per-window kmean (f32) + kv^T (bf16) ----------------
template<int WS>
__global__ __launch_bounds__(256)
void k_winkv(const float* __restrict__ kall, const float* __restrict__ vall,
             float* __restrict__ km, ushort* __restrict__ kvT) {
  constexpr int NWIN = (HSW - WS)/(WS/2) + 1;
  constexpr int NK = WS*WS;
  __shared__ __align__(16) float kl[32][128];
  __shared__ __align__(16) float vl[32][128];
  int w = blockIdx.x;
  int b = w / (NWIN*NWIN);
  int rem = w - b*(NWIN*NWIN);
  int wi = rem / NWIN, wj = rem - (rem/NWIN)*NWIN;
  int y0 = wi*(WS/2), x0 = wj*(WS/2);
  int t = threadIdx.x;
  int h = t >> 6, d = (t>>1)&31, ep = t&1, e0 = ep*16;
  float acc[16];
  #pragma unroll
  for (int k2 = 0; k2 < 16; ++k2) acc[k2] = 0.f;
  float ksum = 0.f;
  for (int n0 = 0; n0 < NK; n0 += 32) {
    __syncthreads();
    #pragma unroll
    for (int e = t; e < 4096; e += 256) {
      int c = e & 127, rr = e >> 7;
      int n = n0 + rr;
      int py = y0 + n / WS, px = x0 + (n - (n/WS)*WS);
      size_t pix = (size_t)b*HSP + (size_t)py*HSW + px;
      kl[rr][c] = kall[pix*CB + c];
      vl[rr][c] = vall[pix*CB + c];
    }
    __syncthreads();
    #pragma unroll 4
    for (int rr = 0; rr < 32; ++rr) {
      float kd = kl[rr][h*32+d];
      ksum += kd;
      #pragma unroll
      for (int k4 = 0; k4 < 4; ++k4) {
        float4 v4 = *(const float4*)&vl[rr][h*32+e0+k4*4];
        acc[k4*4+0] += kd*v4.x;
        acc[k4*4+1] += kd*v4.y;
        acc[k4*4+2] += kd*v4.z;
        acc[k4*4+3] += kd*v4.w;
      }
    }
  }
  // kvT[e][d] layout per head: base + h*1024 + e*32 + d
  ushort* kvp = kvT + (size_t)w*4096 + h*1024 + d;
  #pragma unroll
  for (int k2 = 0; k2 < 16; ++k2)
    kvp[(size_t)(e0+k2)*32] = f2bf(acc[k2] * (1.f/WS));
  if (ep == 0) km[(size_t)w*128 + h*32 + d] = ksum * (1.f/NK);
}

// ---------------- MFMA gather-fold ----------------
// block = 8x8 pixel tile (64 rows), 4 waves, wave = head.
// A: q rows (bf16, global direct). B: kv^T (bf16, global direct).
// z-denominators for all 8 window slots via one MFMA per M-tile (B = kmean columns).
__global__ __launch_bounds__(256)
void k_fold_mfma(const ushort* __restrict__ qbf,
                 const float* __restrict__ km8, const ushort* __restrict__ kv8T,
                 const float* __restrict__ km16, const ushort* __restrict__ kv16T,
                 const float* __restrict__ wwt, float* __restrict__ accimg) {
  int bid = blockIdx.x;
  int bb = bid >> 8;
  int tile = bid & 255;
  int y0 = (tile >> 4) * 8, x0 = (tile & 15) * 8;
  int t = threadIdx.x;
  int h = t >> 6;          // wave = head
  int l = t & 63;
  int lr = l & 15;         // A-row / B-col / C-col
  int lg = l >> 4;         // k-group (8 k's each); C-row-group

  // A fragments: 4 M-tiles of 16 rows
  bf16x8 aq[4];
  #pragma unroll
  for (int mt = 0; mt < 4; ++mt) {
    int row = mt*16 + lr;
    size_t pix = (size_t)bb*LP + (size_t)(y0 + (row>>3))*LW + (x0 + (row&7));
    aq[mt] = *(const bf16x8*)(qbf + pix*CB + h*32 + lg*8);
  }

  float ww0 = wwt[0], ww1 = wwt[1];

  // kmean B-fragment: col = window slot (0..7: 4x ws8 then 4x ws16), k = lg*8+j
  bf16x8 kmf = {0,0,0,0,0,0,0,0};
  {
    int s = lr;
    int wsi = (s >> 2) & 1;
    int n = wsi ? 7 : 15;
    int ar = (y0 >> (3+wsi)) - 1 + ((s>>1)&1);
    int ac = (x0 >> (3+wsi)) - 1 + (s&1);
    if (s < 8 && ar >= 0 && ar < n && ac >= 0 && ac < n) {
      size_t w = ((size_t)bb*n + ar)*n + ac;
      const float* kmp = (wsi ? km16 : km8) + w*(size_t)CB + h*32 + lg*8;
      #pragma unroll
      for (int j = 0; j < 8; ++j) kmf[j] = (short)f2bf(kmp[j]);
    }
  }
  f32x4 z4 = {0.f,0.f,0.f,0.f};
  f32x4 fm[4];
  #pragma unroll
  for (int mt = 0; mt < 4; ++mt) {
    f32x4 zf = __builtin_amdgcn_mfma_f32_16x16x32_bf16(aq[mt], kmf, z4, 0,0,0);
    float wwl = ((lr >> 2) & 1) ? ww1 : ww0;
    #pragma unroll
    for (int r = 0; r < 4; ++r) fm[mt][r] = wwl / (zf[r] + 1e-6f);
  }

  float acc0[4][4], acc1[4][4];
  #pragma unroll
  for (int mt = 0; mt < 4; ++mt)
    #pragma unroll
    for (int r = 0; r < 4; ++r) { acc0[mt][r] = 0.f; acc1[mt][r] = 0.f; }

  #pragma unroll
  for (int s = 0; s < 8; ++s) {
    const int wsi = s >> 2;
    const int n = wsi ? 7 : 15;
    int ar = (y0 >> (3+wsi)) - 1 + ((s>>1)&1);
    int ac = (x0 >> (3+wsi)) - 1 + (s&1);
    if (ar < 0 || ar >= n || ac < 0 || ac >= n) continue;  // block-uniform
    size_t w = ((size_t)bb*n + ar)*n + ac;
    const ushort* kvp = (wsi ? kv16T : kv8T) + w*4096 + h*1024 + lg*8;
    bf16x8 b0 = *(const bf16x8*)(kvp + (size_t)lr*32);
    bf16x8 b1 = *(const bf16x8*)(kvp + (size_t)(16+lr)*32);
    #pragma unroll
    for (int mt = 0; mt < 4; ++mt) {
      f32x4 pv0 = __builtin_amdgcn_mfma_f32_16x16x32_bf16(aq[mt], b0, z4, 0,0,0);
      f32x4 pv1 = __builtin_amdgcn_mfma_f32_16x16x32_bf16(aq[mt], b1, z4, 0,0,0);
      #pragma unroll
      for (int r = 0; r < 4; ++r) {
        float fv = __shfl(fm[mt][r], (l & 48) | s, 64);
        acc0[mt][r] += fv * pv0[r];
        acc1[mt][r] += fv * pv1[r];
      }
    }
  }

  #pragma unroll
  for (int mt = 0; mt < 4; ++mt)
    #pragma unroll
    for (int r = 0; r < 4; ++r) {
      int row = mt*16 + lg*4 + r;
      size_t pix = (size_t)bb*LP + (size_t)(y0 + (row>>3))*LW + (x0 + (row&7));
      float* op = accimg + pix*(size_t)CB + h*32 + lr;
      op[0]  = acc0[mt][r];
      op[16] = acc1[mt][r];
    }
}

// ---------------- final: out = 0.5*(acc@wo.T + bo*mult); final = a*out + (1-a)*low ----------------
__global__ __launch_bounds__(256)
void k_final(const float* __restrict__ accimg, const float* __restrict__ wo,
             const float* __restrict__ bo, const float* __restrict__ low,
             const float* __restrict__ alpha,
             float* __restrict__ out0, float* __restrict__ out1) {
  __shared__ __align__(16) float Al[32][68];
  __shared__ __align__(16) float Wl[32][132];
  int t = threadIdx.x;
  size_t pixbase = (size_t)blockIdx.x * 64;
  int b = (int)(pixbase / LP);
  int prel = (int)(pixbase - (size_t)b * LP);
  int py = prel >> 7;
  int px0 = prel & 127;
  int tx = t & 15, ty = t >> 4;
  float acc[4][8];
  #pragma unroll
  for (int i = 0; i < 4; ++i)
    #pragma unroll
    for (int j = 0; j < 8; ++j) acc[i][j] = 0.f;
  for (int c0 = 0; c0 < CB; c0 += 32) {
    __syncthreads();
    #pragma unroll
    for (int e = t; e < 2048; e += 256) {
      int cc = e & 31, pp = e >> 5;
      Al[cc][pp] = accimg[(pixbase + pp)*CB + c0 + cc];
    }
    #pragma unroll
    for (int e = t; e < 4096; e += 256) {
      int cc = e & 31, o = e >> 5;
      Wl[cc][o] = wo[(size_t)o*CB + c0 + cc];
    }
    __syncthreads();
    #pragma unroll 8
    for (int cc = 0; cc < 32; ++cc) {
      float4 a4 = *(const float4*)&Al[cc][ty*4];
      float4 w0 = *(const float4*)&Wl[cc][tx*8];
      float4 w1 = *(const float4*)&Wl[cc][tx*8+4];
      float av[4] = {a4.x, a4.y, a4.z, a4.w};
      float wv[8] = {w0.x,w0.y,w0.z,w0.w,w1.x,w1.y,w1.z,w1.w};
      #pragma unroll
      for (int i = 0; i < 4; ++i)
        #pragma unroll
        for (int j = 0; j < 8; ++j) acc[i][j] += av[i]*wv[j];
    }
  }
  int cy8  = (py >= 8)  + (py <= 119);
  int cy16 = (py >= 16) + (py <= 111);
  float a = alpha[0];
  float multv[4];
  #pragma unroll
  for (int i = 0; i < 4; ++i) {
    int px = px0 + ty*4 + i;
    int cx8  = (px >= 8)  + (px <= 119);
    int cx16 = (px >= 16) + (px <= 111);
    multv[i] = (float)(cy8*cx8 + cy16*cx16);
  }
  #pragma unroll
  for (int j = 0; j < 8; ++j) {
    int o = tx*8 + j;
    float bov = bo[o];
    size_t addr = ((size_t)b*CB + o)*LP + prel + ty*4;
    float4 lw = *(const float4*)(low + addr);
    float g0 = 0.5f*(acc[0][j] + bov*multv[0]);
    float g1 = 0.5f*(acc[1][j] + bov*multv[1]);
    float g2 = 0.5f*(acc[2][j] + bov*multv[2]);
    float g3 = 0.5f*(acc[3][j] + bov*multv[3]);
    *(float4*)(out0 + addr) = make_float4(g0,g1,g2,g3);
    *(float4*)(out1 + addr) = make_float4(a*g0 + (1.f-a)*lw.x,
                                          a*g1 + (1.f-a)*lw.y,
                                          a*g2 + (1.f-a)*lw.z,
                                          a*g3 + (1.f-a)*lw.w);
  }
}

extern "C" void kernel_launch(void* const* d_in, const int* in_sizes, int n_in,
                              void* d_out, int out_size, void* d_ws, size_t ws_size,
                              hipStream_t stream) {
  const float* high  = (const float*)d_in[0];
  const float* low   = (const float*)d_in[1];
  const float* cw    = (const float*)d_in[2];
  const float* cb    = (const float*)d_in[3];
  const float* lng   = (const float*)d_in[4];
  const float* lnb   = (const float*)d_in[5];
  const float* wq    = (const float*)d_in[6];
  const float* bq    = (const float*)d_in[7];
  const float* wk    = (const float*)d_in[8];
  const float* bk    = (const float*)d_in[9];
  const float* wv    = (const float*)d_in[10];
  const float* bv    = (const float*)d_in[11];
  const float* wo    = (const float*)d_in[12];
  const float* bo    = (const float*)d_in[13];
  const float* wwt   = (const float*)d_in[14];
  const float* alpha = (const float*)d_in[15];

  float* ws   = (float*)d_ws;
  float* hs   = ws + OFF_HS;
  ushort* qbf = (ushort*)(ws + OFF_QBF);
  float* kall = ws + OFF_K;
  float* vall = ws + OFF_V;
  float* mrl  = ws + OFF_MRL;
  float* mrh  = ws + OFF_MRH;
  float* km8  = ws + OFF_KM8;
  ushort* kv8T  = (ushort*)(ws + OFF_KV8T);
  float* km16 = ws + OFF_KM16;
  ushort* kv16T = (ushort*)(ws + OFF_KV16T);
  float* accimg = ws + OFF_ACC;

  float* out0 = (float*)d_out;
  float* out1 = out0 + (size_t)NB*CB*LP;

  k_conv<<<512, 256, 0, stream>>>(high, cw, cb, hs);
  k_lnstats<<<512, 256, 0, stream>>>(low, mrl, LP);
  k_lnstats<<<128, 256, 0, stream>>>(hs, mrh, HSP);
  k_proj<1,1><<<2048, 256, 0, stream>>>(low, mrl, lng, lnb, wq, bq, (void*)qbf, LP);
  k_proj<1,0><<<512, 256, 0, stream>>>(hs, mrh, lng, lnb, wk, bk, (void*)kall, HSP);
  k_proj<0,0><<<512, 256, 0, stream>>>(hs, mrh, lng, lnb, wv, bv, (void*)vall, HSP);
  k_winkv<8><<<1800, 256, 0, stream>>>(kall, vall, km8, kv8T);
  k_winkv<16><<<392, 256, 0, stream>>>(kall, vall, km16, kv16T);
  k_fold_mfma<<<2048, 256, 0, stream>>>(qbf, km8, kv8T, km16, kv16T, wwt, accimg);
  k_final<<<2048, 256, 0, stream>>>(accimg, wo, bo, low, alpha, out0, out1);
}

// Round 3
// 314.932 us; speedup vs baseline: 2.2602x; 1.7274x over previous
//
#include <hip/hip_runtime.h>

#define NB 8
#define CH 256
#define CB 128
#define HSW 64
#define HSP (HSW*HSW)   // 4096
#define LW 128
#define LP (LW*LW)      // 16384

typedef __attribute__((ext_vector_type(8))) short bf16x8;
typedef __attribute__((ext_vector_type(4))) float f32x4;

__device__ inline ushort f2bf(float x) {
  uint u = __float_as_uint(x);
  uint r = (u + 0x7fffu + ((u >> 16) & 1u)) >> 16;
  return (ushort)r;
}
__device__ inline float bf2f(uint u) { return __uint_as_float(u << 16); }

// ---- workspace layout (float units) ----
static constexpr size_t S_HS  = (size_t)NB*CB*HSP;       // f32
static constexpr size_t S_QU  = (size_t)NB*LP*CB;        // ushort count
static constexpr size_t S_KVU = (size_t)NB*HSP*CB;       // ushort count

static constexpr size_t OFF_HS    = 0;
static constexpr size_t OFF_QBF   = OFF_HS + S_HS;
static constexpr size_t OFF_KBF   = OFF_QBF + S_QU/2;
static constexpr size_t OFF_VBF   = OFF_KBF + S_KVU/2;
static constexpr size_t OFF_MRL   = OFF_VBF + S_KVU/2;
static constexpr size_t OFF_MRH   = OFF_MRL + (size_t)NB*LP*2;
static constexpr size_t OFF_KM8   = OFF_MRH + (size_t)NB*HSP*2;
static constexpr size_t OFF_KV8T  = OFF_KM8 + (size_t)1800*128;
static constexpr size_t OFF_KM16  = OFF_KV8T + (size_t)1800*4096/2;
static constexpr size_t OFF_KV16T = OFF_KM16 + (size_t)392*128;
static constexpr size_t OFF_ACC   = OFF_KV16T + (size_t)392*4096/2;   // bf16 accimg
static constexpr size_t OFF_WQB   = OFF_ACC + S_QU/2;
static constexpr size_t OFF_WKB   = OFF_WQB + 8192;
static constexpr size_t OFF_WVB   = OFF_WKB + 8192;
static constexpr size_t OFF_WOB   = OFF_WVB + 8192;

// ---------------- weight cast to bf16 ----------------
__global__ __launch_bounds__(256)
void k_cast4(const float* __restrict__ s0, const float* __restrict__ s1,
             const float* __restrict__ s2, const float* __restrict__ s3,
             ushort* __restrict__ d0, ushort* __restrict__ d1,
             ushort* __restrict__ d2, ushort* __restrict__ d3) {
  const float* s = (blockIdx.y == 0) ? s0 : (blockIdx.y == 1) ? s1 : (blockIdx.y == 2) ? s2 : s3;
  ushort* d = (blockIdx.y == 0) ? d0 : (blockIdx.y == 1) ? d1 : (blockIdx.y == 2) ? d2 : d3;
  int i = (blockIdx.x * 256 + threadIdx.x) * 8;
  float4 a = *(const float4*)(s + i);
  float4 b = *(const float4*)(s + i + 4);
  bf16x8 pk;
  pk[0]=(short)f2bf(a.x); pk[1]=(short)f2bf(a.y); pk[2]=(short)f2bf(a.z); pk[3]=(short)f2bf(a.w);
  pk[4]=(short)f2bf(b.x); pk[5]=(short)f2bf(b.y); pk[6]=(short)f2bf(b.z); pk[7]=(short)f2bf(b.w);
  *(bf16x8*)(d + i) = pk;
}

// ---------------- 1x1 conv (f32 vector) ----------------
__global__ __launch_bounds__(256)
void k_conv(const float* __restrict__ high, const float* __restrict__ cw,
            const float* __restrict__ cb, float* __restrict__ hs) {
  __shared__ __align__(16) float wl[64][36];
  int blk = blockIdx.x;
  int oh = blk & 3;
  int pt = (blk >> 2) & 15;
  int b  = blk >> 6;
  int obase = oh * 32;
  int pix = pt * 256 + threadIdx.x;
  const float* xin = high + (size_t)b * CH * HSP + pix;
  float acc[32];
  #pragma unroll
  for (int j = 0; j < 32; ++j) acc[j] = cb[obase + j];
  for (int c0 = 0; c0 < CH; c0 += 64) {
    __syncthreads();
    for (int e = threadIdx.x; e < 64*32; e += 256) {
      int cc = e & 63, j = e >> 6;
      wl[cc][j] = cw[(size_t)(obase + j) * CH + c0 + cc];
    }
    __syncthreads();
    #pragma unroll 4
    for (int cc = 0; cc < 64; ++cc) {
      float x = xin[(size_t)(c0 + cc) * HSP];
      #pragma unroll
      for (int j4 = 0; j4 < 8; ++j4) {
        float4 w = *(const float4*)&wl[cc][j4*4];
        acc[j4*4+0] += x * w.x;
        acc[j4*4+1] += x * w.y;
        acc[j4*4+2] += x * w.z;
        acc[j4*4+3] += x * w.w;
      }
    }
  }
  float* op = hs + ((size_t)b * CB + obase) * HSP + pix;
  #pragma unroll
  for (int j = 0; j < 32; ++j) op[(size_t)j * HSP] = acc[j];
}

// ---------------- per-pixel LayerNorm stats ----------------
__global__ __launch_bounds__(256)
void k_lnstats(const float* __restrict__ x, float* __restrict__ mr, int npix) {
  size_t idx = (size_t)blockIdx.x * 256 + threadIdx.x;
  int b = (int)(idx / (size_t)npix);
  int p = (int)(idx - (size_t)b * npix);
  const float* xp = x + (size_t)b * CB * npix + p;
  float s = 0.f, ss = 0.f;
  #pragma unroll 8
  for (int c = 0; c < CB; ++c) { float v = xp[(size_t)c * npix]; s += v; ss += v * v; }
  float m = s * (1.f / CB);
  float var = ss * (1.f / CB) - m * m;
  mr[2*idx]   = m;
  mr[2*idx+1] = rsqrtf(fmaxf(var, 0.f) + 1e-5f);
}

// ---------------- MFMA LN+linear proj: y[pix][o] bf16 = act(LN(x)@W.T + b) ----------------
// block: 64 pixels x 128 outputs, 4 waves (wave = 32-out slab). K=128.
template<int ACT>
__global__ __launch_bounds__(256)
void k_projm(const float* __restrict__ x, const float* __restrict__ mr,
             const float* __restrict__ lng, const float* __restrict__ lnb,
             const ushort* __restrict__ Wbf, const float* __restrict__ bias,
             ushort* __restrict__ y, int npix) {
  __shared__ __align__(16) ushort As[64*136];   // row stride 272B = 17 x 16B slots
  __shared__ float gl[128], bl[128], bias_s[128];
  int t = threadIdx.x;
  size_t pixbase = (size_t)blockIdx.x * 64;
  int b = (int)(pixbase / (size_t)npix);
  int prel = (int)(pixbase - (size_t)b * npix);
  const float* xb = x + (size_t)b * CB * npix + prel;
  if (t < 128) { gl[t] = lng[t]; bl[t] = lnb[t]; bias_s[t] = bias[t]; }
  __syncthreads();
  // stage: thread owns pixel p, channel slab of 32
  {
    int p = t & 63;
    int c0 = (t >> 6) * 32;
    float m = mr[2*(pixbase + p)];
    float r = mr[2*(pixbase + p) + 1];
    #pragma unroll
    for (int cc = 0; cc < 32; cc += 8) {
      bf16x8 pk;
      #pragma unroll
      for (int j = 0; j < 8; ++j) {
        float v = xb[(size_t)(c0 + cc + j) * npix + p];
        pk[j] = (short)f2bf((v - m) * r * gl[c0+cc+j] + bl[c0+cc+j]);
      }
      *(bf16x8*)&As[p*136 + c0 + cc] = pk;
    }
  }
  __syncthreads();
  int l = t & 63, h = t >> 6;
  int lr = l & 15, lg = l >> 4;
  int n0 = h * 32;
  f32x4 acc[4][2];
  #pragma unroll
  for (int mt = 0; mt < 4; ++mt)
    #pragma unroll
    for (int nt = 0; nt < 2; ++nt) acc[mt][nt] = (f32x4){0.f,0.f,0.f,0.f};
  #pragma unroll
  for (int k0 = 0; k0 < 128; k0 += 32) {
    bf16x8 a[4], bf[2];
    #pragma unroll
    for (int mt = 0; mt < 4; ++mt)
      a[mt] = *(bf16x8*)&As[(mt*16+lr)*136 + k0 + lg*8];
    #pragma unroll
    for (int nt = 0; nt < 2; ++nt)
      bf[nt] = *(const bf16x8*)(Wbf + (size_t)(n0 + nt*16 + lr)*128 + k0 + lg*8);
    #pragma unroll
    for (int mt = 0; mt < 4; ++mt)
      #pragma unroll
      for (int nt = 0; nt < 2; ++nt)
        acc[mt][nt] = __builtin_amdgcn_mfma_f32_16x16x32_bf16(a[mt], bf[nt], acc[mt][nt], 0,0,0);
  }
  __syncthreads();
  // C -> LDS pixel-major bf16 (reuse As)
  #pragma unroll
  for (int mt = 0; mt < 4; ++mt)
    #pragma unroll
    for (int nt = 0; nt < 2; ++nt) {
      int o = n0 + nt*16 + lr;
      float bv = bias_s[o];
      #pragma unroll
      for (int r = 0; r < 4; ++r) {
        int row = mt*16 + lg*4 + r;
        float v = acc[mt][nt][r] + bv;
        if (ACT) v = (v > 0.f) ? v + 1.f : __expf(v);   // elu+1
        As[row*136 + o] = f2bf(v);
      }
    }
  __syncthreads();
  #pragma unroll
  for (int pass = 0; pass < 4; ++pass) {
    int p = (t >> 4) + pass*16;
    int c = (t & 15) * 8;
    *(bf16x8*)(y + (pixbase + p)*(size_t)CB + c) = *(bf16x8*)&As[p*136 + c];
  }
}

// ---------------- per-window kmean (f32) + kv^T (bf16), bf16 inputs ----------------
template<int WS>
__global__ __launch_bounds__(256)
void k_winkv(const ushort* __restrict__ kall, const ushort* __restrict__ vall,
             float* __restrict__ km, ushort* __restrict__ kvT) {
  constexpr int NWIN = (HSW - WS)/(WS/2) + 1;
  constexpr int NK = WS*WS;
  __shared__ __align__(16) float kl[32][128];
  __shared__ __align__(16) float vl[32][128];
  int w = blockIdx.x;
  int b = w / (NWIN*NWIN);
  int rem = w - b*(NWIN*NWIN);
  int wi = rem / NWIN, wj = rem - (rem/NWIN)*NWIN;
  int y0 = wi*(WS/2), x0 = wj*(WS/2);
  int t = threadIdx.x;
  int h = t >> 6, d = (t>>1)&31, ep = t&1, e0 = ep*16;
  float acc[16];
  #pragma unroll
  for (int k2 = 0; k2 < 16; ++k2) acc[k2] = 0.f;
  float ksum = 0.f;
  for (int n0 = 0; n0 < NK; n0 += 32) {
    __syncthreads();
    #pragma unroll
    for (int e = t; e < 2048; e += 256) {
      int c2 = e & 63, rr = e >> 6;
      int n = n0 + rr;
      int py = y0 + n / WS, px = x0 + (n - (n/WS)*WS);
      size_t base = ((size_t)b*HSP + (size_t)py*HSW + px)*CB + c2*2;
      uint kw = *(const uint*)(kall + base);
      uint vw = *(const uint*)(vall + base);
      *(float2*)&kl[rr][c2*2] = make_float2(bf2f(kw & 0xffffu), bf2f(kw >> 16));
      *(float2*)&vl[rr][c2*2] = make_float2(bf2f(vw & 0xffffu), bf2f(vw >> 16));
    }
    __syncthreads();
    #pragma unroll 4
    for (int rr = 0; rr < 32; ++rr) {
      float kd = kl[rr][h*32+d];
      ksum += kd;
      #pragma unroll
      for (int k4 = 0; k4 < 4; ++k4) {
        float4 v4 = *(const float4*)&vl[rr][h*32+e0+k4*4];
        acc[k4*4+0] += kd*v4.x;
        acc[k4*4+1] += kd*v4.y;
        acc[k4*4+2] += kd*v4.z;
        acc[k4*4+3] += kd*v4.w;
      }
    }
  }
  ushort* kvp = kvT + (size_t)w*4096 + h*1024 + d;
  #pragma unroll
  for (int k2 = 0; k2 < 16; ++k2)
    kvp[(size_t)(e0+k2)*32] = f2bf(acc[k2] * (1.f/WS));
  if (ep == 0) km[(size_t)w*128 + h*32 + d] = ksum * (1.f/NK);
}

// ---------------- MFMA gather-fold, bf16 accimg output ----------------
__global__ __launch_bounds__(256)
void k_fold_mfma(const ushort* __restrict__ qbf,
                 const float* __restrict__ km8, const ushort* __restrict__ kv8T,
                 const float* __restrict__ km16, const ushort* __restrict__ kv16T,
                 const float* __restrict__ wwt, ushort* __restrict__ accbf) {
  int bid = blockIdx.x;
  int bb = bid >> 8;
  int tile = bid & 255;
  int y0 = (tile >> 4) * 8, x0 = (tile & 15) * 8;
  int t = threadIdx.x;
  int h = t >> 6;
  int l = t & 63;
  int lr = l & 15;
  int lg = l >> 4;

  bf16x8 aq[4];
  #pragma unroll
  for (int mt = 0; mt < 4; ++mt) {
    int row = mt*16 + lr;
    size_t pix = (size_t)bb*LP + (size_t)(y0 + (row>>3))*LW + (x0 + (row&7));
    aq[mt] = *(const bf16x8*)(qbf + pix*CB + h*32 + lg*8);
  }

  float ww0 = wwt[0], ww1 = wwt[1];

  bf16x8 kmf = {0,0,0,0,0,0,0,0};
  {
    int s = lr;
    int wsi = (s >> 2) & 1;
    int n = wsi ? 7 : 15;
    int ar = (y0 >> (3+wsi)) - 1 + ((s>>1)&1);
    int ac = (x0 >> (3+wsi)) - 1 + (s&1);
    if (s < 8 && ar >= 0 && ar < n && ac >= 0 && ac < n) {
      size_t w = ((size_t)bb*n + ar)*n + ac;
      const float* kmp = (wsi ? km16 : km8) + w*(size_t)CB + h*32 + lg*8;
      #pragma unroll
      for (int j = 0; j < 8; ++j) kmf[j] = (short)f2bf(kmp[j]);
    }
  }
  f32x4 z4 = {0.f,0.f,0.f,0.f};
  f32x4 fm[4];
  #pragma unroll
  for (int mt = 0; mt < 4; ++mt) {
    f32x4 zf = __builtin_amdgcn_mfma_f32_16x16x32_bf16(aq[mt], kmf, z4, 0,0,0);
    float wwl = ((lr >> 2) & 1) ? ww1 : ww0;
    #pragma unroll
    for (int r = 0; r < 4; ++r) fm[mt][r] = wwl / (zf[r] + 1e-6f);
  }

  float acc0[4][4], acc1[4][4];
  #pragma unroll
  for (int mt = 0; mt < 4; ++mt)
    #pragma unroll
    for (int r = 0; r < 4; ++r) { acc0[mt][r] = 0.f; acc1[mt][r] = 0.f; }

  #pragma unroll
  for (int s = 0; s < 8; ++s) {
    const int wsi = s >> 2;
    const int n = wsi ? 7 : 15;
    int ar = (y0 >> (3+wsi)) - 1 + ((s>>1)&1);
    int ac = (x0 >> (3+wsi)) - 1 + (s&1);
    if (ar < 0 || ar >= n || ac < 0 || ac >= n) continue;
    size_t w = ((size_t)bb*n + ar)*n + ac;
    const ushort* kvp = (wsi ? kv16T : kv8T) + w*4096 + h*1024 + lg*8;
    bf16x8 b0 = *(const bf16x8*)(kvp + (size_t)lr*32);
    bf16x8 b1 = *(const bf16x8*)(kvp + (size_t)(16+lr)*32);
    #pragma unroll
    for (int mt = 0; mt < 4; ++mt) {
      f32x4 pv0 = __builtin_amdgcn_mfma_f32_16x16x32_bf16(aq[mt], b0, z4, 0,0,0);
      f32x4 pv1 = __builtin_amdgcn_mfma_f32_16x16x32_bf16(aq[mt], b1, z4, 0,0,0);
      #pragma unroll
      for (int r = 0; r < 4; ++r) {
        float fv = __shfl(fm[mt][r], (l & 48) | s, 64);
        acc0[mt][r] += fv * pv0[r];
        acc1[mt][r] += fv * pv1[r];
      }
    }
  }

  #pragma unroll
  for (int mt = 0; mt < 4; ++mt)
    #pragma unroll
    for (int r = 0; r < 4; ++r) {
      int row = mt*16 + lg*4 + r;
      size_t pix = (size_t)bb*LP + (size_t)(y0 + (row>>3))*LW + (x0 + (row&7));
      ushort* op = accbf + pix*(size_t)CB + h*32 + lr;
      op[0]  = f2bf(acc0[mt][r]);
      op[16] = f2bf(acc1[mt][r]);
    }
}

// ---------------- MFMA final: out0=0.5*(acc@wo.T + bo*mult); out1 = a*out0+(1-a)*low ----------------
__global__ __launch_bounds__(256)
void k_finalm(const ushort* __restrict__ accbf, const ushort* __restrict__ wobf,
              const float* __restrict__ bo, const float* __restrict__ low,
              const float* __restrict__ alpha,
              float* __restrict__ out0, float* __restrict__ out1) {
  __shared__ __align__(16) ushort As[64*136];
  __shared__ __align__(16) float Cs[128*68];
  int t = threadIdx.x;
  size_t pixbase = (size_t)blockIdx.x * 64;
  int b = (int)(pixbase >> 14);
  int prel = (int)(pixbase & (size_t)(LP-1));
  // stage A (straight copy accbf -> As)
  #pragma unroll
  for (int pass = 0; pass < 4; ++pass) {
    int p = (t >> 4) + pass*16;
    int c = (t & 15) * 8;
    *(bf16x8*)&As[p*136 + c] = *(const bf16x8*)(accbf + (pixbase + p)*(size_t)CB + c);
  }
  __syncthreads();
  int l = t & 63, h = t >> 6;
  int lr = l & 15, lg = l >> 4;
  int n0 = h * 32;
  f32x4 acc[4][2];
  #pragma unroll
  for (int mt = 0; mt < 4; ++mt)
    #pragma unroll
    for (int nt = 0; nt < 2; ++nt) acc[mt][nt] = (f32x4){0.f,0.f,0.f,0.f};
  #pragma unroll
  for (int k0 = 0; k0 < 128; k0 += 32) {
    bf16x8 a[4], bf[2];
    #pragma unroll
    for (int mt = 0; mt < 4; ++mt)
      a[mt] = *(bf16x8*)&As[(mt*16+lr)*136 + k0 + lg*8];
    #pragma unroll
    for (int nt = 0; nt < 2; ++nt)
      bf[nt] = *(const bf16x8*)(wobf + (size_t)(n0 + nt*16 + lr)*128 + k0 + lg*8);
    #pragma unroll
    for (int mt = 0; mt < 4; ++mt)
      #pragma unroll
      for (int nt = 0; nt < 2; ++nt)
        acc[mt][nt] = __builtin_amdgcn_mfma_f32_16x16x32_bf16(a[mt], bf[nt], acc[mt][nt], 0,0,0);
  }
  // C -> Cs[o][p] f32
  #pragma unroll
  for (int mt = 0; mt < 4; ++mt)
    #pragma unroll
    for (int nt = 0; nt < 2; ++nt) {
      int o = n0 + nt*16 + lr;
      #pragma unroll
      for (int r = 0; r < 4; ++r) {
        int row = mt*16 + lg*4 + r;
        Cs[o*68 + row] = acc[mt][nt][r];
      }
    }
  __syncthreads();
  int py = prel >> 7;
  int cy8  = (py >= 8)  + (py <= 119);
  int cy16 = (py >= 16) + (py <= 111);
  float a = alpha[0];
  int px_base = (prel & 127) + (t & 15)*4;
  int p0 = (t & 15)*4;
  float mult[4];
  #pragma unroll
  for (int i = 0; i < 4; ++i) {
    int px = px_base + i;
    int cx8  = (px >= 8)  + (px <= 119);
    int cx16 = (px >= 16) + (px <= 111);
    mult[i] = (float)(cy8*cx8 + cy16*cx16);
  }
  #pragma unroll
  for (int pass = 0; pass < 8; ++pass) {
    int o = (t >> 4) + pass*16;
    float4 c4 = *(float4*)&Cs[o*68 + p0];
    float bov = bo[o];
    size_t addr = ((size_t)b*CB + o)*LP + prel + p0;
    float4 lw = *(const float4*)(low + addr);
    float g0 = 0.5f*(c4.x + bov*mult[0]);
    float g1 = 0.5f*(c4.y + bov*mult[1]);
    float g2 = 0.5f*(c4.z + bov*mult[2]);
    float g3 = 0.5f*(c4.w + bov*mult[3]);
    *(float4*)(out0 + addr) = make_float4(g0,g1,g2,g3);
    *(float4*)(out1 + addr) = make_float4(a*g0 + (1.f-a)*lw.x,
                                          a*g1 + (1.f-a)*lw.y,
                                          a*g2 + (1.f-a)*lw.z,
                                          a*g3 + (1.f-a)*lw.w);
  }
}

extern "C" void kernel_launch(void* const* d_in, const int* in_sizes, int n_in,
                              void* d_out, int out_size, void* d_ws, size_t ws_size,
                              hipStream_t stream) {
  const float* high  = (const float*)d_in[0];
  const float* low   = (const float*)d_in[1];
  const float* cw    = (const float*)d_in[2];
  const float* cb    = (const float*)d_in[3];
  const float* lng   = (const float*)d_in[4];
  const float* lnb   = (const float*)d_in[5];
  const float* wq    = (const float*)d_in[6];
  const float* bq    = (const float*)d_in[7];
  const float* wk    = (const float*)d_in[8];
  const float* bk    = (const float*)d_in[9];
  const float* wv    = (const float*)d_in[10];
  const float* bv    = (const float*)d_in[11];
  const float* wo    = (const float*)d_in[12];
  const float* bo    = (const float*)d_in[13];
  const float* wwt   = (const float*)d_in[14];
  const float* alpha = (const float*)d_in[15];

  float* ws   = (float*)d_ws;
  float* hs   = ws + OFF_HS;
  ushort* qbf = (ushort*)(ws + OFF_QBF);
  ushort* kbf = (ushort*)(ws + OFF_KBF);
  ushort* vbf = (ushort*)(ws + OFF_VBF);
  float* mrl  = ws + OFF_MRL;
  float* mrh  = ws + OFF_MRH;
  float* km8  = ws + OFF_KM8;
  ushort* kv8T  = (ushort*)(ws + OFF_KV8T);
  float* km16 = ws + OFF_KM16;
  ushort* kv16T = (ushort*)(ws + OFF_KV16T);
  ushort* accbf = (ushort*)(ws + OFF_ACC);
  ushort* wqb = (ushort*)(ws + OFF_WQB);
  ushort* wkb = (ushort*)(ws + OFF_WKB);
  ushort* wvb = (ushort*)(ws + OFF_WVB);
  ushort* wob = (ushort*)(ws + OFF_WOB);

  float* out0 = (float*)d_out;
  float* out1 = out0 + (size_t)NB*CB*LP;

  k_cast4<<<dim3(8,4), 256, 0, stream>>>(wq, wk, wv, wo, wqb, wkb, wvb, wob);
  k_conv<<<512, 256, 0, stream>>>(high, cw, cb, hs);
  k_lnstats<<<512, 256, 0, stream>>>(low, mrl, LP);
  k_lnstats<<<128, 256, 0, stream>>>(hs, mrh, HSP);
  k_projm<1><<<2048, 256, 0, stream>>>(low, mrl, lng, lnb, wqb, bq, qbf, LP);
  k_projm<1><<<512, 256, 0, stream>>>(hs, mrh, lng, lnb, wkb, bk, kbf, HSP);
  k_projm<0><<<512, 256, 0, stream>>>(hs, mrh, lng, lnb, wvb, bv, vbf, HSP);
  k_winkv<8><<<1800, 256, 0, stream>>>(kbf, vbf, km8, kv8T);
  k_winkv<16><<<392, 256, 0, stream>>>(kbf, vbf, km16, kv16T);
  k_fold_mfma<<<2048, 256, 0, stream>>>(qbf, km8, kv8T, km16, kv16T, wwt, accbf);
  k_finalm<<<2048, 256, 0, stream>>>(accbf, wob, bo, low, alpha, out0, out1);
}

// Round 5
// 199.867 us; speedup vs baseline: 3.5614x; 1.5757x over previous
//
#include <hip/hip_runtime.h>

#define NB 8
#define CH 256
#define CB 128
#define HSW 64
#define HSP (HSW*HSW)   // 4096
#define LW 128
#define LP (LW*LW)      // 16384

typedef __attribute__((ext_vector_type(8))) short bf16x8;
typedef __attribute__((ext_vector_type(4))) float f32x4;

__device__ inline ushort f2bf(float x) {
  uint u = __float_as_uint(x);
  uint r = (u + 0x7fffu + ((u >> 16) & 1u)) >> 16;
  return (ushort)r;
}
__device__ inline float bf2f(uint u) { return __uint_as_float(u << 16); }

// ---- workspace layout (float units) ----
static constexpr size_t S_QU  = (size_t)NB*LP*CB;        // ushort count (16.7M)
static constexpr size_t S_KVU = (size_t)NB*HSP*CB;       // ushort count (4.2M)

static constexpr size_t OFF_QBF   = 0;
static constexpr size_t OFF_KBF   = OFF_QBF + S_QU/2;
static constexpr size_t OFF_VBF   = OFF_KBF + S_KVU/2;
static constexpr size_t OFF_KM8   = OFF_VBF + S_KVU/2;
static constexpr size_t OFF_KV8T  = OFF_KM8 + (size_t)1800*128;
static constexpr size_t OFF_KM16  = OFF_KV8T + (size_t)1800*4096/2;
static constexpr size_t OFF_KV16T = OFF_KM16 + (size_t)392*128;
static constexpr size_t OFF_ACC   = OFF_KV16T + (size_t)392*4096/2;   // bf16 accimg
static constexpr size_t OFF_WQB   = OFF_ACC + S_QU/2;
static constexpr size_t OFF_WKB   = OFF_WQB + 8192;
static constexpr size_t OFF_WVB   = OFF_WKB + 8192;
static constexpr size_t OFF_WOB   = OFF_WVB + 8192;
static constexpr size_t OFF_CWB   = OFF_WOB + 8192;                   // 32768 ushorts

// ---------------- weight casts to bf16 (wq,wk,wv,wo 128x128; cw 128x256) ----------------
__global__ __launch_bounds__(256)
void k_castw(const float* __restrict__ s0, const float* __restrict__ s1,
             const float* __restrict__ s2, const float* __restrict__ s3,
             const float* __restrict__ s4,
             ushort* __restrict__ d0, ushort* __restrict__ d1,
             ushort* __restrict__ d2, ushort* __restrict__ d3,
             ushort* __restrict__ d4) {
  int y = blockIdx.y;
  const float* s; ushort* d; int n;
  if (y == 0)      { s = s0; d = d0; n = 16384; }
  else if (y == 1) { s = s1; d = d1; n = 16384; }
  else if (y == 2) { s = s2; d = d2; n = 16384; }
  else if (y == 3) { s = s3; d = d3; n = 16384; }
  else             { s = s4; d = d4; n = 32768; }
  int i = (blockIdx.x * 256 + threadIdx.x) * 8;
  if (i >= n) return;
  float4 a = *(const float4*)(s + i);
  float4 b = *(const float4*)(s + i + 4);
  bf16x8 pk;
  pk[0]=(short)f2bf(a.x); pk[1]=(short)f2bf(a.y); pk[2]=(short)f2bf(a.z); pk[3]=(short)f2bf(a.w);
  pk[4]=(short)f2bf(b.x); pk[5]=(short)f2bf(b.y); pk[6]=(short)f2bf(b.z); pk[7]=(short)f2bf(b.w);
  *(bf16x8*)(d + i) = pk;
}

// ---------------- fused conv(MFMA) + LN-stats + LN + k/v projections (MFMA) ----------------
// block = 64 pixels of hs. A1: raw high bf16 [64][264] (256ch + pad); A2: LN'd hs bf16 [64][136].
#define A1S 264
__global__ __launch_bounds__(256)
void k_convkv(const float* __restrict__ high, const ushort* __restrict__ cwb,
              const float* __restrict__ cb, const float* __restrict__ lng,
              const float* __restrict__ lnb,
              const ushort* __restrict__ wkb, const float* __restrict__ bk,
              const ushort* __restrict__ wvb, const float* __restrict__ bv,
              ushort* __restrict__ kbf, ushort* __restrict__ vbf) {
  __shared__ __align__(16) ushort As1[64*A1S];
  __shared__ __align__(16) ushort As2[64*136];
  __shared__ float red[512];
  __shared__ float stat_m[64], stat_r[64];
  int t = threadIdx.x;
  size_t pixbase = (size_t)blockIdx.x * 64;
  int b = blockIdx.x >> 6;                 // 64 blocks per batch
  int prel = (int)(pixbase & (HSP - 1));
  const float* xb = high + (size_t)b*CH*HSP + prel;

  // stage high -> As1 bf16 (channel-pair packed b32 writes)
  {
    int p = t & 63;
    int cp = (t >> 6) * 2;
    #pragma unroll 4
    for (int pass = 0; pass < 32; ++pass) {
      int c = pass*8 + cp;
      float v0 = xb[(size_t)c*HSP + p];
      float v1 = xb[(size_t)(c+1)*HSP + p];
      uint pk = (uint)f2bf(v0) | ((uint)f2bf(v1) << 16);
      *(uint*)&As1[p*A1S + c] = pk;
    }
  }
  __syncthreads();

  int l = t & 63, h = t >> 6;
  int lr = l & 15, lg = l >> 4;
  int n0 = h * 32;

  // conv MFMA: C[pix][out], wave h owns output cols n0..n0+31
  f32x4 acc[4][2];
  #pragma unroll
  for (int mt = 0; mt < 4; ++mt)
    #pragma unroll
    for (int nt = 0; nt < 2; ++nt) acc[mt][nt] = (f32x4){0.f,0.f,0.f,0.f};
  #pragma unroll
  for (int k0 = 0; k0 < 256; k0 += 32) {
    bf16x8 a[4], bw[2];
    #pragma unroll
    for (int mt = 0; mt < 4; ++mt)
      a[mt] = *(bf16x8*)&As1[(mt*16+lr)*A1S + k0 + lg*8];
    #pragma unroll
    for (int nt = 0; nt < 2; ++nt)
      bw[nt] = *(const bf16x8*)(cwb + (size_t)(n0 + nt*16 + lr)*256 + k0 + lg*8);
    #pragma unroll
    for (int mt = 0; mt < 4; ++mt)
      #pragma unroll
      for (int nt = 0; nt < 2; ++nt)
        acc[mt][nt] = __builtin_amdgcn_mfma_f32_16x16x32_bf16(a[mt], bw[nt], acc[mt][nt], 0,0,0);
  }
  // conv bias (before LN stats, matching reference)
  {
    float cb0 = cb[n0 + lr], cb1 = cb[n0 + 16 + lr];
    #pragma unroll
    for (int mt = 0; mt < 4; ++mt)
      #pragma unroll
      for (int r = 0; r < 4; ++r) { acc[mt][0][r] += cb0; acc[mt][1][r] += cb1; }
  }
  // LN stats: reduce over 128 cols (16 lr-lanes x 2 regs per wave, then 4 waves via LDS)
  #pragma unroll
  for (int mt = 0; mt < 4; ++mt)
    #pragma unroll
    for (int r = 0; r < 4; ++r) {
      float a0 = acc[mt][0][r], a1 = acc[mt][1][r];
      float s = a0 + a1, ss = a0*a0 + a1*a1;
      #pragma unroll
      for (int off = 1; off < 16; off <<= 1) {
        s  += __shfl_xor(s, off, 64);
        ss += __shfl_xor(ss, off, 64);
      }
      if (lr == 0) {
        int p = mt*16 + lg*4 + r;
        red[h*64 + p] = s;
        red[256 + h*64 + p] = ss;
      }
    }
  __syncthreads();
  if (t < 64) {
    float s  = red[t] + red[64+t] + red[128+t] + red[192+t];
    float ss = red[256+t] + red[320+t] + red[384+t] + red[448+t];
    float m = s * (1.f/128.f);
    float var = ss * (1.f/128.f) - m*m;
    stat_m[t] = m;
    stat_r[t] = rsqrtf(fmaxf(var, 0.f) + 1e-5f);
  }
  __syncthreads();
  // LN-apply from regs -> As2 bf16
  {
    float g0 = lng[n0+lr], b0 = lnb[n0+lr];
    float g1 = lng[n0+16+lr], b1 = lnb[n0+16+lr];
    #pragma unroll
    for (int mt = 0; mt < 4; ++mt)
      #pragma unroll
      for (int r = 0; r < 4; ++r) {
        int p = mt*16 + lg*4 + r;
        float m = stat_m[p], rr = stat_r[p];
        As2[p*136 + n0 + lr]      = f2bf((acc[mt][0][r] - m)*rr*g0 + b0);
        As2[p*136 + n0 + 16 + lr] = f2bf((acc[mt][1][r] - m)*rr*g1 + b1);
      }
  }
  __syncthreads();

  // k & v projection MFMAs share A-fragments
  f32x4 ak[4][2], av[4][2];
  #pragma unroll
  for (int mt = 0; mt < 4; ++mt)
    #pragma unroll
    for (int nt = 0; nt < 2; ++nt) { ak[mt][nt] = (f32x4){0.f,0.f,0.f,0.f}; av[mt][nt] = (f32x4){0.f,0.f,0.f,0.f}; }
  #pragma unroll
  for (int k0 = 0; k0 < 128; k0 += 32) {
    bf16x8 a[4], bkf[2], bvf[2];
    #pragma unroll
    for (int mt = 0; mt < 4; ++mt)
      a[mt] = *(bf16x8*)&As2[(mt*16+lr)*136 + k0 + lg*8];
    #pragma unroll
    for (int nt = 0; nt < 2; ++nt) {
      bkf[nt] = *(const bf16x8*)(wkb + (size_t)(n0 + nt*16 + lr)*128 + k0 + lg*8);
      bvf[nt] = *(const bf16x8*)(wvb + (size_t)(n0 + nt*16 + lr)*128 + k0 + lg*8);
    }
    #pragma unroll
    for (int mt = 0; mt < 4; ++mt)
      #pragma unroll
      for (int nt = 0; nt < 2; ++nt) {
        ak[mt][nt] = __builtin_amdgcn_mfma_f32_16x16x32_bf16(a[mt], bkf[nt], ak[mt][nt], 0,0,0);
        av[mt][nt] = __builtin_amdgcn_mfma_f32_16x16x32_bf16(a[mt], bvf[nt], av[mt][nt], 0,0,0);
      }
  }
  __syncthreads();
  // k epilogue (bias + elu+1) -> As2 -> store
  {
    float bk0 = bk[n0+lr], bk1 = bk[n0+16+lr];
    #pragma unroll
    for (int mt = 0; mt < 4; ++mt)
      #pragma unroll
      for (int r = 0; r < 4; ++r) {
        int p = mt*16 + lg*4 + r;
        float v0 = ak[mt][0][r] + bk0;
        float v1 = ak[mt][1][r] + bk1;
        v0 = (v0 > 0.f) ? v0 + 1.f : __expf(v0);
        v1 = (v1 > 0.f) ? v1 + 1.f : __expf(v1);
        As2[p*136 + n0 + lr]      = f2bf(v0);
        As2[p*136 + n0 + 16 + lr] = f2bf(v1);
      }
  }
  __syncthreads();
  #pragma unroll
  for (int pass = 0; pass < 4; ++pass) {
    int p = (t >> 4) + pass*16;
    int c = (t & 15) * 8;
    *(bf16x8*)(kbf + (pixbase + p)*(size_t)CB + c) = *(bf16x8*)&As2[p*136 + c];
  }
  __syncthreads();
  // v epilogue (bias, no act) -> As2 -> store
  {
    float bv0 = bv[n0+lr], bv1 = bv[n0+16+lr];
    #pragma unroll
    for (int mt = 0; mt < 4; ++mt)
      #pragma unroll
      for (int r = 0; r < 4; ++r) {
        int p = mt*16 + lg*4 + r;
        As2[p*136 + n0 + lr]      = f2bf(av[mt][0][r] + bv0);
        As2[p*136 + n0 + 16 + lr] = f2bf(av[mt][1][r] + bv1);
      }
  }
  __syncthreads();
  #pragma unroll
  for (int pass = 0; pass < 4; ++pass) {
    int p = (t >> 4) + pass*16;
    int c = (t & 15) * 8;
    *(bf16x8*)(vbf + (pixbase + p)*(size_t)CB + c) = *(bf16x8*)&As2[p*136 + c];
  }
}

// ---------------- fused LN-stats + LN + q projection (MFMA) ----------------
__global__ __launch_bounds__(256)
void k_projq(const float* __restrict__ low,
             const float* __restrict__ lng, const float* __restrict__ lnb,
             const ushort* __restrict__ wqb, const float* __restrict__ bq,
             ushort* __restrict__ qbf) {
  __shared__ __align__(16) ushort As[64*136];
  __shared__ float red[512];
  __shared__ float stat_m[64], stat_r[64];
  int t = threadIdx.x;
  size_t pixbase = (size_t)blockIdx.x * 64;
  int b = (int)(pixbase >> 14);
  int prel = (int)(pixbase & (size_t)(LP - 1));
  const float* xb = low + (size_t)b*CB*LP + prel;
  int p = t & 63, cs = t >> 6;
  float x[32];
  {
    float s = 0.f, ss = 0.f;
    #pragma unroll
    for (int j = 0; j < 32; ++j) {
      x[j] = xb[(size_t)(cs*32 + j)*LP + p];
      s += x[j]; ss += x[j]*x[j];
    }
    red[cs*64 + p] = s;
    red[256 + cs*64 + p] = ss;
  }
  __syncthreads();
  if (t < 64) {
    float s  = red[t] + red[64+t] + red[128+t] + red[192+t];
    float ss = red[256+t] + red[320+t] + red[384+t] + red[448+t];
    float m = s * (1.f/128.f);
    float var = ss * (1.f/128.f) - m*m;
    stat_m[t] = m;
    stat_r[t] = rsqrtf(fmaxf(var, 0.f) + 1e-5f);
  }
  __syncthreads();
  {
    float m = stat_m[p], r = stat_r[p];
    #pragma unroll
    for (int j8 = 0; j8 < 4; ++j8) {
      bf16x8 pk;
      #pragma unroll
      for (int jj = 0; jj < 8; ++jj) {
        int c = cs*32 + j8*8 + jj;
        pk[jj] = (short)f2bf((x[j8*8 + jj] - m)*r*lng[c] + lnb[c]);
      }
      *(bf16x8*)&As[p*136 + cs*32 + j8*8] = pk;
    }
  }
  __syncthreads();
  int l = t & 63, h = t >> 6;
  int lr = l & 15, lg = l >> 4;
  int n0 = h * 32;
  f32x4 acc[4][2];
  #pragma unroll
  for (int mt = 0; mt < 4; ++mt)
    #pragma unroll
    for (int nt = 0; nt < 2; ++nt) acc[mt][nt] = (f32x4){0.f,0.f,0.f,0.f};
  #pragma unroll
  for (int k0 = 0; k0 < 128; k0 += 32) {
    bf16x8 a[4], bf[2];
    #pragma unroll
    for (int mt = 0; mt < 4; ++mt)
      a[mt] = *(bf16x8*)&As[(mt*16+lr)*136 + k0 + lg*8];
    #pragma unroll
    for (int nt = 0; nt < 2; ++nt)
      bf[nt] = *(const bf16x8*)(wqb + (size_t)(n0 + nt*16 + lr)*128 + k0 + lg*8);
    #pragma unroll
    for (int mt = 0; mt < 4; ++mt)
      #pragma unroll
      for (int nt = 0; nt < 2; ++nt)
        acc[mt][nt] = __builtin_amdgcn_mfma_f32_16x16x32_bf16(a[mt], bf[nt], acc[mt][nt], 0,0,0);
  }
  __syncthreads();
  {
    float b0 = bq[n0+lr], b1 = bq[n0+16+lr];
    #pragma unroll
    for (int mt = 0; mt < 4; ++mt)
      #pragma unroll
      for (int r = 0; r < 4; ++r) {
        int pp = mt*16 + lg*4 + r;
        float v0 = acc[mt][0][r] + b0;
        float v1 = acc[mt][1][r] + b1;
        v0 = (v0 > 0.f) ? v0 + 1.f : __expf(v0);
        v1 = (v1 > 0.f) ? v1 + 1.f : __expf(v1);
        As[pp*136 + n0 + lr]      = f2bf(v0);
        As[pp*136 + n0 + 16 + lr] = f2bf(v1);
      }
  }
  __syncthreads();
  #pragma unroll
  for (int pass = 0; pass < 4; ++pass) {
    int pp = (t >> 4) + pass*16;
    int c = (t & 15) * 8;
    *(bf16x8*)(qbf + (pixbase + pp)*(size_t)CB + c) = *(bf16x8*)&As[pp*136 + c];
  }
}

// ---------------- per-window kmean (f32) + kv^T (bf16), bf16 inputs ----------------
template<int WS>
__global__ __launch_bounds__(256)
void k_winkv(const ushort* __restrict__ kall, const ushort* __restrict__ vall,
             float* __restrict__ km, ushort* __restrict__ kvT) {
  constexpr int NWIN = (HSW - WS)/(WS/2) + 1;
  constexpr int NK = WS*WS;
  __shared__ __align__(16) float kl[32][128];
  __shared__ __align__(16) float vl[32][128];
  int w = blockIdx.x;
  int b = w / (NWIN*NWIN);
  int rem = w - b*(NWIN*NWIN);
  int wi = rem / NWIN, wj = rem - (rem/NWIN)*NWIN;
  int y0 = wi*(WS/2), x0 = wj*(WS/2);
  int t = threadIdx.x;
  int h = t >> 6, d = (t>>1)&31, ep = t&1, e0 = ep*16;
  float acc[16];
  #pragma unroll
  for (int k2 = 0; k2 < 16; ++k2) acc[k2] = 0.f;
  float ksum = 0.f;
  for (int n0 = 0; n0 < NK; n0 += 32) {
    __syncthreads();
    #pragma unroll
    for (int e = t; e < 2048; e += 256) {
      int c2 = e & 63, rr = e >> 6;
      int n = n0 + rr;
      int py = y0 + n / WS, px = x0 + (n - (n/WS)*WS);
      size_t base = ((size_t)b*HSP + (size_t)py*HSW + px)*CB + c2*2;
      uint kw = *(const uint*)(kall + base);
      uint vw = *(const uint*)(vall + base);
      *(float2*)&kl[rr][c2*2] = make_float2(bf2f(kw & 0xffffu), bf2f(kw >> 16));
      *(float2*)&vl[rr][c2*2] = make_float2(bf2f(vw & 0xffffu), bf2f(vw >> 16));
    }
    __syncthreads();
    #pragma unroll 4
    for (int rr = 0; rr < 32; ++rr) {
      float kd = kl[rr][h*32+d];
      ksum += kd;
      #pragma unroll
      for (int k4 = 0; k4 < 4; ++k4) {
        float4 v4 = *(const float4*)&vl[rr][h*32+e0+k4*4];
        acc[k4*4+0] += kd*v4.x;
        acc[k4*4+1] += kd*v4.y;
        acc[k4*4+2] += kd*v4.z;
        acc[k4*4+3] += kd*v4.w;
      }
    }
  }
  ushort* kvp = kvT + (size_t)w*4096 + h*1024 + d;
  #pragma unroll
  for (int k2 = 0; k2 < 16; ++k2)
    kvp[(size_t)(e0+k2)*32] = f2bf(acc[k2] * (1.f/WS));
  if (ep == 0) km[(size_t)w*128 + h*32 + d] = ksum * (1.f/NK);
}

// ---------------- MFMA gather-fold, bf16 accimg output ----------------
__global__ __launch_bounds__(256)
void k_fold_mfma(const ushort* __restrict__ qbf,
                 const float* __restrict__ km8, const ushort* __restrict__ kv8T,
                 const float* __restrict__ km16, const ushort* __restrict__ kv16T,
                 const float* __restrict__ wwt, ushort* __restrict__ accbf) {
  int bid = blockIdx.x;
  int bb = bid >> 8;
  int tile = bid & 255;
  int y0 = (tile >> 4) * 8, x0 = (tile & 15) * 8;
  int t = threadIdx.x;
  int h = t >> 6;
  int l = t & 63;
  int lr = l & 15;
  int lg = l >> 4;

  bf16x8 aq[4];
  #pragma unroll
  for (int mt = 0; mt < 4; ++mt) {
    int row = mt*16 + lr;
    size_t pix = (size_t)bb*LP + (size_t)(y0 + (row>>3))*LW + (x0 + (row&7));
    aq[mt] = *(const bf16x8*)(qbf + pix*CB + h*32 + lg*8);
  }

  float ww0 = wwt[0], ww1 = wwt[1];

  bf16x8 kmf = {0,0,0,0,0,0,0,0};
  {
    int s = lr;
    int wsi = (s >> 2) & 1;
    int n = wsi ? 7 : 15;
    int ar = (y0 >> (3+wsi)) - 1 + ((s>>1)&1);
    int ac = (x0 >> (3+wsi)) - 1 + (s&1);
    if (s < 8 && ar >= 0 && ar < n && ac >= 0 && ac < n) {
      size_t w = ((size_t)bb*n + ar)*n + ac;
      const float* kmp = (wsi ? km16 : km8) + w*(size_t)CB + h*32 + lg*8;
      #pragma unroll
      for (int j = 0; j < 8; ++j) kmf[j] = (short)f2bf(kmp[j]);
    }
  }
  f32x4 z4 = {0.f,0.f,0.f,0.f};
  f32x4 fm[4];
  #pragma unroll
  for (int mt = 0; mt < 4; ++mt) {
    f32x4 zf = __builtin_amdgcn_mfma_f32_16x16x32_bf16(aq[mt], kmf, z4, 0,0,0);
    float wwl = ((lr >> 2) & 1) ? ww1 : ww0;
    #pragma unroll
    for (int r = 0; r < 4; ++r) fm[mt][r] = wwl / (zf[r] + 1e-6f);
  }

  float acc0[4][4], acc1[4][4];
  #pragma unroll
  for (int mt = 0; mt < 4; ++mt)
    #pragma unroll
    for (int r = 0; r < 4; ++r) { acc0[mt][r] = 0.f; acc1[mt][r] = 0.f; }

  #pragma unroll
  for (int s = 0; s < 8; ++s) {
    const int wsi = s >> 2;
    const int n = wsi ? 7 : 15;
    int ar = (y0 >> (3+wsi)) - 1 + ((s>>1)&1);
    int ac = (x0 >> (3+wsi)) - 1 + (s&1);
    if (ar < 0 || ar >= n || ac < 0 || ac >= n) continue;
    size_t w = ((size_t)bb*n + ar)*n + ac;
    const ushort* kvp = (wsi ? kv16T : kv8T) + w*4096 + h*1024 + lg*8;
    bf16x8 b0 = *(const bf16x8*)(kvp + (size_t)lr*32);
    bf16x8 b1 = *(const bf16x8*)(kvp + (size_t)(16+lr)*32);
    #pragma unroll
    for (int mt = 0; mt < 4; ++mt) {
      f32x4 pv0 = __builtin_amdgcn_mfma_f32_16x16x32_bf16(aq[mt], b0, z4, 0,0,0);
      f32x4 pv1 = __builtin_amdgcn_mfma_f32_16x16x32_bf16(aq[mt], b1, z4, 0,0,0);
      #pragma unroll
      for (int r = 0; r < 4; ++r) {
        float fv = __shfl(fm[mt][r], (l & 48) | s, 64);
        acc0[mt][r] += fv * pv0[r];
        acc1[mt][r] += fv * pv1[r];
      }
    }
  }

  #pragma unroll
  for (int mt = 0; mt < 4; ++mt)
    #pragma unroll
    for (int r = 0; r < 4; ++r) {
      int row = mt*16 + lg*4 + r;
      size_t pix = (size_t)bb*LP + (size_t)(y0 + (row>>3))*LW + (x0 + (row&7));
      ushort* op = accbf + pix*(size_t)CB + h*32 + lr;
      op[0]  = f2bf(acc0[mt][r]);
      op[16] = f2bf(acc1[mt][r]);
    }
}

// ---------------- MFMA final: out0=0.5*(acc@wo.T + bo*mult); out1 = a*out0+(1-a)*low ----------------
__global__ __launch_bounds__(256)
void k_finalm(const ushort* __restrict__ accbf, const ushort* __restrict__ wobf,
              const float* __restrict__ bo, const float* __restrict__ low,
              const float* __restrict__ alpha,
              float* __restrict__ out0, float* __restrict__ out1) {
  __shared__ __align__(16) ushort As[64*136];
  __shared__ __align__(16) float Cs[128*68];
  int t = threadIdx.x;
  size_t pixbase = (size_t)blockIdx.x * 64;
  int b = (int)(pixbase >> 14);
  int prel = (int)(pixbase & (size_t)(LP-1));
  #pragma unroll
  for (int pass = 0; pass < 4; ++pass) {
    int p = (t >> 4) + pass*16;
    int c = (t & 15) * 8;
    *(bf16x8*)&As[p*136 + c] = *(const bf16x8*)(accbf + (pixbase + p)*(size_t)CB + c);
  }
  __syncthreads();
  int l = t & 63, h = t >> 6;
  int lr = l & 15, lg = l >> 4;
  int n0 = h * 32;
  f32x4 acc[4][2];
  #pragma unroll
  for (int mt = 0; mt < 4; ++mt)
    #pragma unroll
    for (int nt = 0; nt < 2; ++nt) acc[mt][nt] = (f32x4){0.f,0.f,0.f,0.f};
  #pragma unroll
  for (int k0 = 0; k0 < 128; k0 += 32) {
    bf16x8 a[4], bf[2];
    #pragma unroll
    for (int mt = 0; mt < 4; ++mt)
      a[mt] = *(bf16x8*)&As[(mt*16+lr)*136 + k0 + lg*8];
    #pragma unroll
    for (int nt = 0; nt < 2; ++nt)
      bf[nt] = *(const bf16x8*)(wobf + (size_t)(n0 + nt*16 + lr)*128 + k0 + lg*8);
    #pragma unroll
    for (int mt = 0; mt < 4; ++mt)
      #pragma unroll
      for (int nt = 0; nt < 2; ++nt)
        acc[mt][nt] = __builtin_amdgcn_mfma_f32_16x16x32_bf16(a[mt], bf[nt], acc[mt][nt], 0,0,0);
  }
  #pragma unroll
  for (int mt = 0; mt < 4; ++mt)
    #pragma unroll
    for (int nt = 0; nt < 2; ++nt) {
      int o = n0 + nt*16 + lr;
      #pragma unroll
      for (int r = 0; r < 4; ++r) {
        int row = mt*16 + lg*4 + r;
        Cs[o*68 + row] = acc[mt][nt][r];
      }
    }
  __syncthreads();
  int py = prel >> 7;
  int cy8  = (py >= 8)  + (py <= 119);
  int cy16 = (py >= 16) + (py <= 111);
  float a = alpha[0];
  int px_base = (prel & 127) + (t & 15)*4;
  int p0 = (t & 15)*4;
  float mult[4];
  #pragma unroll
  for (int i = 0; i < 4; ++i) {
    int px = px_base + i;
    int cx8  = (px >= 8)  + (px <= 119);
    int cx16 = (px >= 16) + (px <= 111);
    mult[i] = (float)(cy8*cx8 + cy16*cx16);
  }
  #pragma unroll
  for (int pass = 0; pass < 8; ++pass) {
    int o = (t >> 4) + pass*16;
    float4 c4 = *(float4*)&Cs[o*68 + p0];
    float bov = bo[o];
    size_t addr = ((size_t)b*CB + o)*LP + prel + p0;
    float4 lw = *(const float4*)(low + addr);
    float g0 = 0.5f*(c4.x + bov*mult[0]);
    float g1 = 0.5f*(c4.y + bov*mult[1]);
    float g2 = 0.5f*(c4.z + bov*mult[2]);
    float g3 = 0.5f*(c4.w + bov*mult[3]);
    *(float4*)(out0 + addr) = make_float4(g0,g1,g2,g3);
    *(float4*)(out1 + addr) = make_float4(a*g0 + (1.f-a)*lw.x,
                                          a*g1 + (1.f-a)*lw.y,
                                          a*g2 + (1.f-a)*lw.z,
                                          a*g3 + (1.f-a)*lw.w);
  }
}

extern "C" void kernel_launch(void* const* d_in, const int* in_sizes, int n_in,
                              void* d_out, int out_size, void* d_ws, size_t ws_size,
                              hipStream_t stream) {
  const float* high  = (const float*)d_in[0];
  const float* low   = (const float*)d_in[1];
  const float* cw    = (const float*)d_in[2];
  const float* cb    = (const float*)d_in[3];
  const float* lng   = (const float*)d_in[4];
  const float* lnb   = (const float*)d_in[5];
  const float* wq    = (const float*)d_in[6];
  const float* bq    = (const float*)d_in[7];
  const float* wk    = (const float*)d_in[8];
  const float* bk    = (const float*)d_in[9];
  const float* wv    = (const float*)d_in[10];
  const float* bv    = (const float*)d_in[11];
  const float* wo    = (const float*)d_in[12];
  const float* bo    = (const float*)d_in[13];
  const float* wwt   = (const float*)d_in[14];
  const float* alpha = (const float*)d_in[15];

  float* ws   = (float*)d_ws;
  ushort* qbf = (ushort*)(ws + OFF_QBF);
  ushort* kbf = (ushort*)(ws + OFF_KBF);
  ushort* vbf = (ushort*)(ws + OFF_VBF);
  float* km8  = ws + OFF_KM8;
  ushort* kv8T  = (ushort*)(ws + OFF_KV8T);
  float* km16 = ws + OFF_KM16;
  ushort* kv16T = (ushort*)(ws + OFF_KV16T);
  ushort* accbf = (ushort*)(ws + OFF_ACC);
  ushort* wqb = (ushort*)(ws + OFF_WQB);
  ushort* wkb = (ushort*)(ws + OFF_WKB);
  ushort* wvb = (ushort*)(ws + OFF_WVB);
  ushort* wob = (ushort*)(ws + OFF_WOB);
  ushort* cwb = (ushort*)(ws + OFF_CWB);

  float* out0 = (float*)d_out;
  float* out1 = out0 + (size_t)NB*CB*LP;

  k_castw<<<dim3(16,5), 256, 0, stream>>>(wq, wk, wv, wo, cw, wqb, wkb, wvb, wob, cwb);
  k_convkv<<<512, 256, 0, stream>>>(high, cwb, cb, lng, lnb, wkb, bk, wvb, bv, kbf, vbf);
  k_projq<<<2048, 256, 0, stream>>>(low, lng, lnb, wqb, bq, qbf);
  k_winkv<8><<<1800, 256, 0, stream>>>(kbf, vbf, km8, kv8T);
  k_winkv<16><<<392, 256, 0, stream>>>(kbf, vbf, km16, kv16T);
  k_fold_mfma<<<2048, 256, 0, stream>>>(qbf, km8, kv8T, km16, kv16T, wwt, accbf);
  k_finalm<<<2048, 256, 0, stream>>>(accbf, wob, bo, low, alpha, out0, out1);
}

// Round 6
// 188.434 us; speedup vs baseline: 3.7774x; 1.0607x over previous
//
#include <hip/hip_runtime.h>

#define NB 8
#define CH 256
#define CB 128
#define HSW 64
#define HSP (HSW*HSW)   // 4096
#define LW 128
#define LP (LW*LW)      // 16384

typedef __attribute__((ext_vector_type(8))) short bf16x8;
typedef __attribute__((ext_vector_type(4))) float f32x4;

__device__ inline ushort f2bf(float x) {
  uint u = __float_as_uint(x);
  uint r = (u + 0x7fffu + ((u >> 16) & 1u)) >> 16;
  return (ushort)r;
}
__device__ inline float bf2f(uint u) { return __uint_as_float(u << 16); }

// ---- workspace layout (float units) ----
static constexpr size_t S_QU  = (size_t)NB*LP*CB;        // ushort count (16.7M)
static constexpr size_t S_KVU = (size_t)NB*HSP*CB;       // ushort count (4.2M)

static constexpr size_t OFF_KBF   = 0;
static constexpr size_t OFF_VBF   = OFF_KBF + S_KVU/2;
static constexpr size_t OFF_KM8   = OFF_VBF + S_KVU/2;
static constexpr size_t OFF_KV8T  = OFF_KM8 + (size_t)1800*128;
static constexpr size_t OFF_KM16  = OFF_KV8T + (size_t)1800*4096/2;
static constexpr size_t OFF_KV16T = OFF_KM16 + (size_t)392*128;
static constexpr size_t OFF_ACC   = OFF_KV16T + (size_t)392*4096/2;   // bf16 accimg
static constexpr size_t OFF_WQB   = OFF_ACC + S_QU/2;
static constexpr size_t OFF_WKB   = OFF_WQB + 8192;
static constexpr size_t OFF_WVB   = OFF_WKB + 8192;
static constexpr size_t OFF_WOB   = OFF_WVB + 8192;
static constexpr size_t OFF_CWB   = OFF_WOB + 8192;                   // 32768 ushorts

// ---------------- weight casts to bf16 (wq,wk,wv,wo 128x128; cw 128x256) ----------------
__global__ __launch_bounds__(256)
void k_castw(const float* __restrict__ s0, const float* __restrict__ s1,
             const float* __restrict__ s2, const float* __restrict__ s3,
             const float* __restrict__ s4,
             ushort* __restrict__ d0, ushort* __restrict__ d1,
             ushort* __restrict__ d2, ushort* __restrict__ d3,
             ushort* __restrict__ d4) {
  int y = blockIdx.y;
  const float* s; ushort* d; int n;
  if (y == 0)      { s = s0; d = d0; n = 16384; }
  else if (y == 1) { s = s1; d = d1; n = 16384; }
  else if (y == 2) { s = s2; d = d2; n = 16384; }
  else if (y == 3) { s = s3; d = d3; n = 16384; }
  else             { s = s4; d = d4; n = 32768; }
  int i = (blockIdx.x * 256 + threadIdx.x) * 8;
  if (i >= n) return;
  float4 a = *(const float4*)(s + i);
  float4 b = *(const float4*)(s + i + 4);
  bf16x8 pk;
  pk[0]=(short)f2bf(a.x); pk[1]=(short)f2bf(a.y); pk[2]=(short)f2bf(a.z); pk[3]=(short)f2bf(a.w);
  pk[4]=(short)f2bf(b.x); pk[5]=(short)f2bf(b.y); pk[6]=(short)f2bf(b.z); pk[7]=(short)f2bf(b.w);
  *(bf16x8*)(d + i) = pk;
}

// ---------------- fused conv(MFMA) + LN-stats + LN + k/v projections (MFMA) ----------------
#define A1S 264
__global__ __launch_bounds__(256)
void k_convkv(const float* __restrict__ high, const ushort* __restrict__ cwb,
              const float* __restrict__ cb, const float* __restrict__ lng,
              const float* __restrict__ lnb,
              const ushort* __restrict__ wkb, const float* __restrict__ bk,
              const ushort* __restrict__ wvb, const float* __restrict__ bv,
              ushort* __restrict__ kbf, ushort* __restrict__ vbf) {
  __shared__ __align__(16) ushort As1[64*A1S];
  __shared__ __align__(16) ushort As2[64*136];
  __shared__ float red[512];
  __shared__ float stat_m[64], stat_r[64];
  int t = threadIdx.x;
  size_t pixbase = (size_t)blockIdx.x * 64;
  int b = blockIdx.x >> 6;                 // 64 blocks per batch
  int prel = (int)(pixbase & (HSP - 1));
  const float* xb = high + (size_t)b*CH*HSP + prel;

  {
    int p = t & 63;
    int cp = (t >> 6) * 2;
    #pragma unroll 4
    for (int pass = 0; pass < 32; ++pass) {
      int c = pass*8 + cp;
      float v0 = xb[(size_t)c*HSP + p];
      float v1 = xb[(size_t)(c+1)*HSP + p];
      uint pk = (uint)f2bf(v0) | ((uint)f2bf(v1) << 16);
      *(uint*)&As1[p*A1S + c] = pk;
    }
  }
  __syncthreads();

  int l = t & 63, h = t >> 6;
  int lr = l & 15, lg = l >> 4;
  int n0 = h * 32;

  f32x4 acc[4][2];
  #pragma unroll
  for (int mt = 0; mt < 4; ++mt)
    #pragma unroll
    for (int nt = 0; nt < 2; ++nt) acc[mt][nt] = (f32x4){0.f,0.f,0.f,0.f};
  #pragma unroll
  for (int k0 = 0; k0 < 256; k0 += 32) {
    bf16x8 a[4], bw[2];
    #pragma unroll
    for (int mt = 0; mt < 4; ++mt)
      a[mt] = *(bf16x8*)&As1[(mt*16+lr)*A1S + k0 + lg*8];
    #pragma unroll
    for (int nt = 0; nt < 2; ++nt)
      bw[nt] = *(const bf16x8*)(cwb + (size_t)(n0 + nt*16 + lr)*256 + k0 + lg*8);
    #pragma unroll
    for (int mt = 0; mt < 4; ++mt)
      #pragma unroll
      for (int nt = 0; nt < 2; ++nt)
        acc[mt][nt] = __builtin_amdgcn_mfma_f32_16x16x32_bf16(a[mt], bw[nt], acc[mt][nt], 0,0,0);
  }
  {
    float cb0 = cb[n0 + lr], cb1 = cb[n0 + 16 + lr];
    #pragma unroll
    for (int mt = 0; mt < 4; ++mt)
      #pragma unroll
      for (int r = 0; r < 4; ++r) { acc[mt][0][r] += cb0; acc[mt][1][r] += cb1; }
  }
  #pragma unroll
  for (int mt = 0; mt < 4; ++mt)
    #pragma unroll
    for (int r = 0; r < 4; ++r) {
      float a0 = acc[mt][0][r], a1 = acc[mt][1][r];
      float s = a0 + a1, ss = a0*a0 + a1*a1;
      #pragma unroll
      for (int off = 1; off < 16; off <<= 1) {
        s  += __shfl_xor(s, off, 64);
        ss += __shfl_xor(ss, off, 64);
      }
      if (lr == 0) {
        int p = mt*16 + lg*4 + r;
        red[h*64 + p] = s;
        red[256 + h*64 + p] = ss;
      }
    }
  __syncthreads();
  if (t < 64) {
    float s  = red[t] + red[64+t] + red[128+t] + red[192+t];
    float ss = red[256+t] + red[320+t] + red[384+t] + red[448+t];
    float m = s * (1.f/128.f);
    float var = ss * (1.f/128.f) - m*m;
    stat_m[t] = m;
    stat_r[t] = rsqrtf(fmaxf(var, 0.f) + 1e-5f);
  }
  __syncthreads();
  {
    float g0 = lng[n0+lr], b0 = lnb[n0+lr];
    float g1 = lng[n0+16+lr], b1 = lnb[n0+16+lr];
    #pragma unroll
    for (int mt = 0; mt < 4; ++mt)
      #pragma unroll
      for (int r = 0; r < 4; ++r) {
        int p = mt*16 + lg*4 + r;
        float m = stat_m[p], rr = stat_r[p];
        As2[p*136 + n0 + lr]      = f2bf((acc[mt][0][r] - m)*rr*g0 + b0);
        As2[p*136 + n0 + 16 + lr] = f2bf((acc[mt][1][r] - m)*rr*g1 + b1);
      }
  }
  __syncthreads();

  f32x4 ak[4][2], av[4][2];
  #pragma unroll
  for (int mt = 0; mt < 4; ++mt)
    #pragma unroll
    for (int nt = 0; nt < 2; ++nt) { ak[mt][nt] = (f32x4){0.f,0.f,0.f,0.f}; av[mt][nt] = (f32x4){0.f,0.f,0.f,0.f}; }
  #pragma unroll
  for (int k0 = 0; k0 < 128; k0 += 32) {
    bf16x8 a[4], bkf[2], bvf[2];
    #pragma unroll
    for (int mt = 0; mt < 4; ++mt)
      a[mt] = *(bf16x8*)&As2[(mt*16+lr)*136 + k0 + lg*8];
    #pragma unroll
    for (int nt = 0; nt < 2; ++nt) {
      bkf[nt] = *(const bf16x8*)(wkb + (size_t)(n0 + nt*16 + lr)*128 + k0 + lg*8);
      bvf[nt] = *(const bf16x8*)(wvb + (size_t)(n0 + nt*16 + lr)*128 + k0 + lg*8);
    }
    #pragma unroll
    for (int mt = 0; mt < 4; ++mt)
      #pragma unroll
      for (int nt = 0; nt < 2; ++nt) {
        ak[mt][nt] = __builtin_amdgcn_mfma_f32_16x16x32_bf16(a[mt], bkf[nt], ak[mt][nt], 0,0,0);
        av[mt][nt] = __builtin_amdgcn_mfma_f32_16x16x32_bf16(a[mt], bvf[nt], av[mt][nt], 0,0,0);
      }
  }
  __syncthreads();
  {
    float bk0 = bk[n0+lr], bk1 = bk[n0+16+lr];
    #pragma unroll
    for (int mt = 0; mt < 4; ++mt)
      #pragma unroll
      for (int r = 0; r < 4; ++r) {
        int p = mt*16 + lg*4 + r;
        float v0 = ak[mt][0][r] + bk0;
        float v1 = ak[mt][1][r] + bk1;
        v0 = (v0 > 0.f) ? v0 + 1.f : __expf(v0);
        v1 = (v1 > 0.f) ? v1 + 1.f : __expf(v1);
        As2[p*136 + n0 + lr]      = f2bf(v0);
        As2[p*136 + n0 + 16 + lr] = f2bf(v1);
      }
  }
  __syncthreads();
  #pragma unroll
  for (int pass = 0; pass < 4; ++pass) {
    int p = (t >> 4) + pass*16;
    int c = (t & 15) * 8;
    *(bf16x8*)(kbf + (pixbase + p)*(size_t)CB + c) = *(bf16x8*)&As2[p*136 + c];
  }
  __syncthreads();
  {
    float bv0 = bv[n0+lr], bv1 = bv[n0+16+lr];
    #pragma unroll
    for (int mt = 0; mt < 4; ++mt)
      #pragma unroll
      for (int r = 0; r < 4; ++r) {
        int p = mt*16 + lg*4 + r;
        As2[p*136 + n0 + lr]      = f2bf(av[mt][0][r] + bv0);
        As2[p*136 + n0 + 16 + lr] = f2bf(av[mt][1][r] + bv1);
      }
  }
  __syncthreads();
  #pragma unroll
  for (int pass = 0; pass < 4; ++pass) {
    int p = (t >> 4) + pass*16;
    int c = (t & 15) * 8;
    *(bf16x8*)(vbf + (pixbase + p)*(size_t)CB + c) = *(bf16x8*)&As2[p*136 + c];
  }
}

// ---------------- per-window kmean (f32) + kv^T (bf16), bf16 inputs ----------------
template<int WS>
__global__ __launch_bounds__(256)
void k_winkv(const ushort* __restrict__ kall, const ushort* __restrict__ vall,
             float* __restrict__ km, ushort* __restrict__ kvT) {
  constexpr int NWIN = (HSW - WS)/(WS/2) + 1;
  constexpr int NK = WS*WS;
  __shared__ __align__(16) float kl[32][128];
  __shared__ __align__(16) float vl[32][128];
  int w = blockIdx.x;
  int b = w / (NWIN*NWIN);
  int rem = w - b*(NWIN*NWIN);
  int wi = rem / NWIN, wj = rem - (rem/NWIN)*NWIN;
  int y0 = wi*(WS/2), x0 = wj*(WS/2);
  int t = threadIdx.x;
  int h = t >> 6, d = (t>>1)&31, ep = t&1, e0 = ep*16;
  float acc[16];
  #pragma unroll
  for (int k2 = 0; k2 < 16; ++k2) acc[k2] = 0.f;
  float ksum = 0.f;
  for (int n0 = 0; n0 < NK; n0 += 32) {
    __syncthreads();
    #pragma unroll
    for (int e = t; e < 2048; e += 256) {
      int c2 = e & 63, rr = e >> 6;
      int n = n0 + rr;
      int py = y0 + n / WS, px = x0 + (n - (n/WS)*WS);
      size_t base = ((size_t)b*HSP + (size_t)py*HSW + px)*CB + c2*2;
      uint kw = *(const uint*)(kall + base);
      uint vw = *(const uint*)(vall + base);
      *(float2*)&kl[rr][c2*2] = make_float2(bf2f(kw & 0xffffu), bf2f(kw >> 16));
      *(float2*)&vl[rr][c2*2] = make_float2(bf2f(vw & 0xffffu), bf2f(vw >> 16));
    }
    __syncthreads();
    #pragma unroll 4
    for (int rr = 0; rr < 32; ++rr) {
      float kd = kl[rr][h*32+d];
      ksum += kd;
      #pragma unroll
      for (int k4 = 0; k4 < 4; ++k4) {
        float4 v4 = *(const float4*)&vl[rr][h*32+e0+k4*4];
        acc[k4*4+0] += kd*v4.x;
        acc[k4*4+1] += kd*v4.y;
        acc[k4*4+2] += kd*v4.z;
        acc[k4*4+3] += kd*v4.w;
      }
    }
  }
  ushort* kvp = kvT + (size_t)w*4096 + h*1024 + d;
  #pragma unroll
  for (int k2 = 0; k2 < 16; ++k2)
    kvp[(size_t)(e0+k2)*32] = f2bf(acc[k2] * (1.f/WS));
  if (ep == 0) km[(size_t)w*128 + h*32 + d] = ksum * (1.f/NK);
}

// ---------------- fused LN + q-proj (MFMA) + gather-fold (MFMA), per 8x8 tile ----------------
__global__ __launch_bounds__(256)
void k_qfold(const float* __restrict__ low,
             const float* __restrict__ lng, const float* __restrict__ lnb,
             const ushort* __restrict__ wqb, const float* __restrict__ bq,
             const float* __restrict__ km8, const ushort* __restrict__ kv8T,
             const float* __restrict__ km16, const ushort* __restrict__ kv16T,
             const float* __restrict__ wwt, ushort* __restrict__ accbf) {
  __shared__ __align__(16) ushort As[64*136];
  __shared__ float red[512];
  __shared__ float stat_m[64], stat_r[64];
  int t = threadIdx.x;
  // XCD chunk swizzle: 2048 blocks, 8 XCDs -> each XCD owns one batch image
  int bid = blockIdx.x;
  int swz = (bid & 7) * 256 + (bid >> 3);
  int bb = swz >> 8;
  int tile = swz & 255;
  int y0 = (tile >> 4) * 8, x0 = (tile & 15) * 8;

  int p = t & 63, cs = t >> 6;
  int ppy = p >> 3, ppx = p & 7;
  const float* xb = low + (size_t)bb*CB*LP + (size_t)(y0+ppy)*LW + (x0+ppx);
  float x[32];
  {
    float s = 0.f, ss = 0.f;
    #pragma unroll
    for (int j = 0; j < 32; ++j) {
      x[j] = xb[(size_t)(cs*32 + j)*LP];
      s += x[j]; ss += x[j]*x[j];
    }
    red[cs*64 + p] = s;
    red[256 + cs*64 + p] = ss;
  }
  __syncthreads();
  if (t < 64) {
    float s  = red[t] + red[64+t] + red[128+t] + red[192+t];
    float ss = red[256+t] + red[320+t] + red[384+t] + red[448+t];
    float m = s * (1.f/128.f);
    float var = ss * (1.f/128.f) - m*m;
    stat_m[t] = m;
    stat_r[t] = rsqrtf(fmaxf(var, 0.f) + 1e-5f);
  }
  __syncthreads();
  {
    float m = stat_m[p], r = stat_r[p];
    #pragma unroll
    for (int j8 = 0; j8 < 4; ++j8) {
      bf16x8 pk;
      #pragma unroll
      for (int jj = 0; jj < 8; ++jj) {
        int c = cs*32 + j8*8 + jj;
        pk[jj] = (short)f2bf((x[j8*8 + jj] - m)*r*lng[c] + lnb[c]);
      }
      *(bf16x8*)&As[p*136 + cs*32 + j8*8] = pk;
    }
  }
  __syncthreads();

  int l = t & 63, h = t >> 6;
  int lr = l & 15, lg = l >> 4;
  int n0 = h * 32;

  // q-GEMM
  f32x4 qa[4][2];
  #pragma unroll
  for (int mt = 0; mt < 4; ++mt)
    #pragma unroll
    for (int nt = 0; nt < 2; ++nt) qa[mt][nt] = (f32x4){0.f,0.f,0.f,0.f};
  #pragma unroll
  for (int k0 = 0; k0 < 128; k0 += 32) {
    bf16x8 a[4], bf[2];
    #pragma unroll
    for (int mt = 0; mt < 4; ++mt)
      a[mt] = *(bf16x8*)&As[(mt*16+lr)*136 + k0 + lg*8];
    #pragma unroll
    for (int nt = 0; nt < 2; ++nt)
      bf[nt] = *(const bf16x8*)(wqb + (size_t)(n0 + nt*16 + lr)*128 + k0 + lg*8);
    #pragma unroll
    for (int mt = 0; mt < 4; ++mt)
      #pragma unroll
      for (int nt = 0; nt < 2; ++nt)
        qa[mt][nt] = __builtin_amdgcn_mfma_f32_16x16x32_bf16(a[mt], bf[nt], qa[mt][nt], 0,0,0);
  }
  __syncthreads();
  // elu+1 epilogue -> As (q, bf16, pixel-major)
  {
    float b0 = bq[n0+lr], b1 = bq[n0+16+lr];
    #pragma unroll
    for (int mt = 0; mt < 4; ++mt)
      #pragma unroll
      for (int r = 0; r < 4; ++r) {
        int pp = mt*16 + lg*4 + r;
        float v0 = qa[mt][0][r] + b0;
        float v1 = qa[mt][1][r] + b1;
        v0 = (v0 > 0.f) ? v0 + 1.f : __expf(v0);
        v1 = (v1 > 0.f) ? v1 + 1.f : __expf(v1);
        As[pp*136 + n0 + lr]      = f2bf(v0);
        As[pp*136 + n0 + 16 + lr] = f2bf(v1);
      }
  }
  __syncthreads();

  // fold: A-frags from As (wave h reads its own head slab)
  bf16x8 aq[4];
  #pragma unroll
  for (int mt = 0; mt < 4; ++mt)
    aq[mt] = *(bf16x8*)&As[(mt*16+lr)*136 + h*32 + lg*8];

  float ww0 = wwt[0], ww1 = wwt[1];

  bf16x8 kmf = {0,0,0,0,0,0,0,0};
  {
    int s = lr;
    int wsi = (s >> 2) & 1;
    int n = wsi ? 7 : 15;
    int ar = (y0 >> (3+wsi)) - 1 + ((s>>1)&1);
    int ac = (x0 >> (3+wsi)) - 1 + (s&1);
    if (s < 8 && ar >= 0 && ar < n && ac >= 0 && ac < n) {
      size_t w = ((size_t)bb*n + ar)*n + ac;
      const float* kmp = (wsi ? km16 : km8) + w*(size_t)CB + h*32 + lg*8;
      #pragma unroll
      for (int j = 0; j < 8; ++j) kmf[j] = (short)f2bf(kmp[j]);
    }
  }
  f32x4 z4 = {0.f,0.f,0.f,0.f};
  f32x4 fm[4];
  #pragma unroll
  for (int mt = 0; mt < 4; ++mt) {
    f32x4 zf = __builtin_amdgcn_mfma_f32_16x16x32_bf16(aq[mt], kmf, z4, 0,0,0);
    float wwl = ((lr >> 2) & 1) ? ww1 : ww0;
    #pragma unroll
    for (int r = 0; r < 4; ++r) fm[mt][r] = wwl / (zf[r] + 1e-6f);
  }

  float acc0[4][4], acc1[4][4];
  #pragma unroll
  for (int mt = 0; mt < 4; ++mt)
    #pragma unroll
    for (int r = 0; r < 4; ++r) { acc0[mt][r] = 0.f; acc1[mt][r] = 0.f; }

  #pragma unroll
  for (int s = 0; s < 8; ++s) {
    const int wsi = s >> 2;
    const int n = wsi ? 7 : 15;
    int ar = (y0 >> (3+wsi)) - 1 + ((s>>1)&1);
    int ac = (x0 >> (3+wsi)) - 1 + (s&1);
    if (ar < 0 || ar >= n || ac < 0 || ac >= n) continue;  // block-uniform
    size_t w = ((size_t)bb*n + ar)*n + ac;
    const ushort* kvp = (wsi ? kv16T : kv8T) + w*4096 + h*1024 + lg*8;
    bf16x8 b0 = *(const bf16x8*)(kvp + (size_t)lr*32);
    bf16x8 b1 = *(const bf16x8*)(kvp + (size_t)(16+lr)*32);
    #pragma unroll
    for (int mt = 0; mt < 4; ++mt) {
      f32x4 pv0 = __builtin_amdgcn_mfma_f32_16x16x32_bf16(aq[mt], b0, z4, 0,0,0);
      f32x4 pv1 = __builtin_amdgcn_mfma_f32_16x16x32_bf16(aq[mt], b1, z4, 0,0,0);
      #pragma unroll
      for (int r = 0; r < 4; ++r) {
        float fv = __shfl(fm[mt][r], (l & 48) | s, 64);
        acc0[mt][r] += fv * pv0[r];
        acc1[mt][r] += fv * pv1[r];
      }
    }
  }
  __syncthreads();
  // acc -> As bf16 (pixel-major), then vectorized global store
  #pragma unroll
  for (int mt = 0; mt < 4; ++mt)
    #pragma unroll
    for (int r = 0; r < 4; ++r) {
      int pp = mt*16 + lg*4 + r;
      As[pp*136 + n0 + lr]      = f2bf(acc0[mt][r]);
      As[pp*136 + n0 + 16 + lr] = f2bf(acc1[mt][r]);
    }
  __syncthreads();
  #pragma unroll
  for (int pass = 0; pass < 4; ++pass) {
    int pp = (t >> 4) + pass*16;
    int c = (t & 15) * 8;
    size_t pix = (size_t)bb*LP + (size_t)(y0 + (pp>>3))*LW + (x0 + (pp&7));
    *(bf16x8*)(accbf + pix*(size_t)CB + c) = *(bf16x8*)&As[pp*136 + c];
  }
}

// ---------------- MFMA final: out0=0.5*(acc@wo.T + bo*mult); out1 = a*out0+(1-a)*low ----------------
__global__ __launch_bounds__(256)
void k_finalm(const ushort* __restrict__ accbf, const ushort* __restrict__ wobf,
              const float* __restrict__ bo, const float* __restrict__ low,
              const float* __restrict__ alpha,
              float* __restrict__ out0, float* __restrict__ out1) {
  __shared__ __align__(16) ushort As[64*136];
  __shared__ __align__(16) float Cs[128*68];
  int t = threadIdx.x;
  size_t pixbase = (size_t)blockIdx.x * 64;
  int b = (int)(pixbase >> 14);
  int prel = (int)(pixbase & (size_t)(LP-1));
  #pragma unroll
  for (int pass = 0; pass < 4; ++pass) {
    int p = (t >> 4) + pass*16;
    int c = (t & 15) * 8;
    *(bf16x8*)&As[p*136 + c] = *(const bf16x8*)(accbf + (pixbase + p)*(size_t)CB + c);
  }
  __syncthreads();
  int l = t & 63, h = t >> 6;
  int lr = l & 15, lg = l >> 4;
  int n0 = h * 32;
  f32x4 acc[4][2];
  #pragma unroll
  for (int mt = 0; mt < 4; ++mt)
    #pragma unroll
    for (int nt = 0; nt < 2; ++nt) acc[mt][nt] = (f32x4){0.f,0.f,0.f,0.f};
  #pragma unroll
  for (int k0 = 0; k0 < 128; k0 += 32) {
    bf16x8 a[4], bf[2];
    #pragma unroll
    for (int mt = 0; mt < 4; ++mt)
      a[mt] = *(bf16x8*)&As[(mt*16+lr)*136 + k0 + lg*8];
    #pragma unroll
    for (int nt = 0; nt < 2; ++nt)
      bf[nt] = *(const bf16x8*)(wobf + (size_t)(n0 + nt*16 + lr)*128 + k0 + lg*8);
    #pragma unroll
    for (int mt = 0; mt < 4; ++mt)
      #pragma unroll
      for (int nt = 0; nt < 2; ++nt)
        acc[mt][nt] = __builtin_amdgcn_mfma_f32_16x16x32_bf16(a[mt], bf[nt], acc[mt][nt], 0,0,0);
  }
  #pragma unroll
  for (int mt = 0; mt < 4; ++mt)
    #pragma unroll
    for (int nt = 0; nt < 2; ++nt) {
      int o = n0 + nt*16 + lr;
      #pragma unroll
      for (int r = 0; r < 4; ++r) {
        int row = mt*16 + lg*4 + r;
        Cs[o*68 + row] = acc[mt][nt][r];
      }
    }
  __syncthreads();
  int py = prel >> 7;
  int cy8  = (py >= 8)  + (py <= 119);
  int cy16 = (py >= 16) + (py <= 111);
  float a = alpha[0];
  int px_base = (prel & 127) + (t & 15)*4;
  int p0 = (t & 15)*4;
  float mult[4];
  #pragma unroll
  for (int i = 0; i < 4; ++i) {
    int px = px_base + i;
    int cx8  = (px >= 8)  + (px <= 119);
    int cx16 = (px >= 16) + (px <= 111);
    mult[i] = (float)(cy8*cx8 + cy16*cx16);
  }
  #pragma unroll
  for (int pass = 0; pass < 8; ++pass) {
    int o = (t >> 4) + pass*16;
    float4 c4 = *(float4*)&Cs[o*68 + p0];
    float bov = bo[o];
    size_t addr = ((size_t)b*CB + o)*LP + prel + p0;
    float4 lw = *(const float4*)(low + addr);
    float g0 = 0.5f*(c4.x + bov*mult[0]);
    float g1 = 0.5f*(c4.y + bov*mult[1]);
    float g2 = 0.5f*(c4.z + bov*mult[2]);
    float g3 = 0.5f*(c4.w + bov*mult[3]);
    *(float4*)(out0 + addr) = make_float4(g0,g1,g2,g3);
    *(float4*)(out1 + addr) = make_float4(a*g0 + (1.f-a)*lw.x,
                                          a*g1 + (1.f-a)*lw.y,
                                          a*g2 + (1.f-a)*lw.z,
                                          a*g3 + (1.f-a)*lw.w);
  }
}

extern "C" void kernel_launch(void* const* d_in, const int* in_sizes, int n_in,
                              void* d_out, int out_size, void* d_ws, size_t ws_size,
                              hipStream_t stream) {
  const float* high  = (const float*)d_in[0];
  const float* low   = (const float*)d_in[1];
  const float* cw    = (const float*)d_in[2];
  const float* cb    = (const float*)d_in[3];
  const float* lng   = (const float*)d_in[4];
  const float* lnb   = (const float*)d_in[5];
  const float* wq    = (const float*)d_in[6];
  const float* bq    = (const float*)d_in[7];
  const float* wk    = (const float*)d_in[8];
  const float* bk    = (const float*)d_in[9];
  const float* wv    = (const float*)d_in[10];
  const float* bv    = (const float*)d_in[11];
  const float* wo    = (const float*)d_in[12];
  const float* bo    = (const float*)d_in[13];
  const float* wwt   = (const float*)d_in[14];
  const float* alpha = (const float*)d_in[15];

  float* ws   = (float*)d_ws;
  ushort* kbf = (ushort*)(ws + OFF_KBF);
  ushort* vbf = (ushort*)(ws + OFF_VBF);
  float* km8  = ws + OFF_KM8;
  ushort* kv8T  = (ushort*)(ws + OFF_KV8T);
  float* km16 = ws + OFF_KM16;
  ushort* kv16T = (ushort*)(ws + OFF_KV16T);
  ushort* accbf = (ushort*)(ws + OFF_ACC);
  ushort* wqb = (ushort*)(ws + OFF_WQB);
  ushort* wkb = (ushort*)(ws + OFF_WKB);
  ushort* wvb = (ushort*)(ws + OFF_WVB);
  ushort* wob = (ushort*)(ws + OFF_WOB);
  ushort* cwb = (ushort*)(ws + OFF_CWB);

  float* out0 = (float*)d_out;
  float* out1 = out0 + (size_t)NB*CB*LP;

  k_castw<<<dim3(16,5), 256, 0, stream>>>(wq, wk, wv, wo, cw, wqb, wkb, wvb, wob, cwb);
  k_convkv<<<512, 256, 0, stream>>>(high, cwb, cb, lng, lnb, wkb, bk, wvb, bv, kbf, vbf);
  k_winkv<8><<<1800, 256, 0, stream>>>(kbf, vbf, km8, kv8T);
  k_winkv<16><<<392, 256, 0, stream>>>(kbf, vbf, km16, kv16T);
  k_qfold<<<2048, 256, 0, stream>>>(low, lng, lnb, wqb, bq, km8, kv8T, km16, kv16T, wwt, accbf);
  k_finalm<<<2048, 256, 0, stream>>>(accbf, wob, bo, low, alpha, out0, out1);
}

// Round 7
// 175.701 us; speedup vs baseline: 4.0512x; 1.0725x over previous
//
#include <hip/hip_runtime.h>

#define NB 8
#define CH 256
#define CB 128
#define HSW 64
#define HSP (HSW*HSW)   // 4096
#define LW 128
#define LP (LW*LW)      // 16384

typedef __attribute__((ext_vector_type(8))) short bf16x8;
typedef __attribute__((ext_vector_type(4))) float f32x4;

__device__ inline ushort f2bf(float x) {
  uint u = __float_as_uint(x);
  uint r = (u + 0x7fffu + ((u >> 16) & 1u)) >> 16;
  return (ushort)r;
}
__device__ inline float bf2f(uint u) { return __uint_as_float(u << 16); }

// ---- workspace layout (float units) ----
static constexpr size_t S_KVU = (size_t)NB*HSP*CB;       // ushort count (4.2M)

static constexpr size_t OFF_KBF   = 0;
static constexpr size_t OFF_VBF   = OFF_KBF + S_KVU/2;
static constexpr size_t OFF_KM8   = OFF_VBF + S_KVU/2;
static constexpr size_t OFF_KV8T  = OFF_KM8 + (size_t)1800*128;
static constexpr size_t OFF_KM16  = OFF_KV8T + (size_t)1800*4096/2;
static constexpr size_t OFF_KV16T = OFF_KM16 + (size_t)392*128;
static constexpr size_t OFF_WQB   = OFF_KV16T + (size_t)392*4096/2;
static constexpr size_t OFF_WKB   = OFF_WQB + 8192;
static constexpr size_t OFF_WVB   = OFF_WKB + 8192;
static constexpr size_t OFF_WOB   = OFF_WVB + 8192;
static constexpr size_t OFF_CWB   = OFF_WOB + 8192;                   // 32768 ushorts

// ---------------- weight casts to bf16 (wq,wk,wv,wo 128x128; cw 128x256) ----------------
__global__ __launch_bounds__(256)
void k_castw(const float* __restrict__ s0, const float* __restrict__ s1,
             const float* __restrict__ s2, const float* __restrict__ s3,
             const float* __restrict__ s4,
             ushort* __restrict__ d0, ushort* __restrict__ d1,
             ushort* __restrict__ d2, ushort* __restrict__ d3,
             ushort* __restrict__ d4) {
  int y = blockIdx.y;
  const float* s; ushort* d; int n;
  if (y == 0)      { s = s0; d = d0; n = 16384; }
  else if (y == 1) { s = s1; d = d1; n = 16384; }
  else if (y == 2) { s = s2; d = d2; n = 16384; }
  else if (y == 3) { s = s3; d = d3; n = 16384; }
  else             { s = s4; d = d4; n = 32768; }
  int i = (blockIdx.x * 256 + threadIdx.x) * 8;
  if (i >= n) return;
  float4 a = *(const float4*)(s + i);
  float4 b = *(const float4*)(s + i + 4);
  bf16x8 pk;
  pk[0]=(short)f2bf(a.x); pk[1]=(short)f2bf(a.y); pk[2]=(short)f2bf(a.z); pk[3]=(short)f2bf(a.w);
  pk[4]=(short)f2bf(b.x); pk[5]=(short)f2bf(b.y); pk[6]=(short)f2bf(b.z); pk[7]=(short)f2bf(b.w);
  *(bf16x8*)(d + i) = pk;
}

// ---------------- fused conv(MFMA) + LN-stats + LN + k/v projections (MFMA) ----------------
#define A1S 264
__global__ __launch_bounds__(256)
void k_convkv(const float* __restrict__ high, const ushort* __restrict__ cwb,
              const float* __restrict__ cb, const float* __restrict__ lng,
              const float* __restrict__ lnb,
              const ushort* __restrict__ wkb, const float* __restrict__ bk,
              const ushort* __restrict__ wvb, const float* __restrict__ bv,
              ushort* __restrict__ kbf, ushort* __restrict__ vbf) {
  __shared__ __align__(16) ushort As1[64*A1S];
  __shared__ __align__(16) ushort As2[64*136];
  __shared__ float red[512];
  __shared__ float stat_m[64], stat_r[64];
  int t = threadIdx.x;
  size_t pixbase = (size_t)blockIdx.x * 64;
  int b = blockIdx.x >> 6;                 // 64 blocks per batch
  int prel = (int)(pixbase & (HSP - 1));
  const float* xb = high + (size_t)b*CH*HSP + prel;

  {
    int p = t & 63;
    int cp = (t >> 6) * 2;
    #pragma unroll 4
    for (int pass = 0; pass < 32; ++pass) {
      int c = pass*8 + cp;
      float v0 = xb[(size_t)c*HSP + p];
      float v1 = xb[(size_t)(c+1)*HSP + p];
      uint pk = (uint)f2bf(v0) | ((uint)f2bf(v1) << 16);
      *(uint*)&As1[p*A1S + c] = pk;
    }
  }
  __syncthreads();

  int l = t & 63, h = t >> 6;
  int lr = l & 15, lg = l >> 4;
  int n0 = h * 32;

  f32x4 acc[4][2];
  #pragma unroll
  for (int mt = 0; mt < 4; ++mt)
    #pragma unroll
    for (int nt = 0; nt < 2; ++nt) acc[mt][nt] = (f32x4){0.f,0.f,0.f,0.f};
  #pragma unroll
  for (int k0 = 0; k0 < 256; k0 += 32) {
    bf16x8 a[4], bw[2];
    #pragma unroll
    for (int mt = 0; mt < 4; ++mt)
      a[mt] = *(bf16x8*)&As1[(mt*16+lr)*A1S + k0 + lg*8];
    #pragma unroll
    for (int nt = 0; nt < 2; ++nt)
      bw[nt] = *(const bf16x8*)(cwb + (size_t)(n0 + nt*16 + lr)*256 + k0 + lg*8);
    #pragma unroll
    for (int mt = 0; mt < 4; ++mt)
      #pragma unroll
      for (int nt = 0; nt < 2; ++nt)
        acc[mt][nt] = __builtin_amdgcn_mfma_f32_16x16x32_bf16(a[mt], bw[nt], acc[mt][nt], 0,0,0);
  }
  {
    float cb0 = cb[n0 + lr], cb1 = cb[n0 + 16 + lr];
    #pragma unroll
    for (int mt = 0; mt < 4; ++mt)
      #pragma unroll
      for (int r = 0; r < 4; ++r) { acc[mt][0][r] += cb0; acc[mt][1][r] += cb1; }
  }
  #pragma unroll
  for (int mt = 0; mt < 4; ++mt)
    #pragma unroll
    for (int r = 0; r < 4; ++r) {
      float a0 = acc[mt][0][r], a1 = acc[mt][1][r];
      float s = a0 + a1, ss = a0*a0 + a1*a1;
      #pragma unroll
      for (int off = 1; off < 16; off <<= 1) {
        s  += __shfl_xor(s, off, 64);
        ss += __shfl_xor(ss, off, 64);
      }
      if (lr == 0) {
        int p = mt*16 + lg*4 + r;
        red[h*64 + p] = s;
        red[256 + h*64 + p] = ss;
      }
    }
  __syncthreads();
  if (t < 64) {
    float s  = red[t] + red[64+t] + red[128+t] + red[192+t];
    float ss = red[256+t] + red[320+t] + red[384+t] + red[448+t];
    float m = s * (1.f/128.f);
    float var = ss * (1.f/128.f) - m*m;
    stat_m[t] = m;
    stat_r[t] = rsqrtf(fmaxf(var, 0.f) + 1e-5f);
  }
  __syncthreads();
  {
    float g0 = lng[n0+lr], b0 = lnb[n0+lr];
    float g1 = lng[n0+16+lr], b1 = lnb[n0+16+lr];
    #pragma unroll
    for (int mt = 0; mt < 4; ++mt)
      #pragma unroll
      for (int r = 0; r < 4; ++r) {
        int p = mt*16 + lg*4 + r;
        float m = stat_m[p], rr = stat_r[p];
        As2[p*136 + n0 + lr]      = f2bf((acc[mt][0][r] - m)*rr*g0 + b0);
        As2[p*136 + n0 + 16 + lr] = f2bf((acc[mt][1][r] - m)*rr*g1 + b1);
      }
  }
  __syncthreads();

  f32x4 ak[4][2], av[4][2];
  #pragma unroll
  for (int mt = 0; mt < 4; ++mt)
    #pragma unroll
    for (int nt = 0; nt < 2; ++nt) { ak[mt][nt] = (f32x4){0.f,0.f,0.f,0.f}; av[mt][nt] = (f32x4){0.f,0.f,0.f,0.f}; }
  #pragma unroll
  for (int k0 = 0; k0 < 128; k0 += 32) {
    bf16x8 a[4], bkf[2], bvf[2];
    #pragma unroll
    for (int mt = 0; mt < 4; ++mt)
      a[mt] = *(bf16x8*)&As2[(mt*16+lr)*136 + k0 + lg*8];
    #pragma unroll
    for (int nt = 0; nt < 2; ++nt) {
      bkf[nt] = *(const bf16x8*)(wkb + (size_t)(n0 + nt*16 + lr)*128 + k0 + lg*8);
      bvf[nt] = *(const bf16x8*)(wvb + (size_t)(n0 + nt*16 + lr)*128 + k0 + lg*8);
    }
    #pragma unroll
    for (int mt = 0; mt < 4; ++mt)
      #pragma unroll
      for (int nt = 0; nt < 2; ++nt) {
        ak[mt][nt] = __builtin_amdgcn_mfma_f32_16x16x32_bf16(a[mt], bkf[nt], ak[mt][nt], 0,0,0);
        av[mt][nt] = __builtin_amdgcn_mfma_f32_16x16x32_bf16(a[mt], bvf[nt], av[mt][nt], 0,0,0);
      }
  }
  __syncthreads();
  {
    float bk0 = bk[n0+lr], bk1 = bk[n0+16+lr];
    #pragma unroll
    for (int mt = 0; mt < 4; ++mt)
      #pragma unroll
      for (int r = 0; r < 4; ++r) {
        int p = mt*16 + lg*4 + r;
        float v0 = ak[mt][0][r] + bk0;
        float v1 = ak[mt][1][r] + bk1;
        v0 = (v0 > 0.f) ? v0 + 1.f : __expf(v0);
        v1 = (v1 > 0.f) ? v1 + 1.f : __expf(v1);
        As2[p*136 + n0 + lr]      = f2bf(v0);
        As2[p*136 + n0 + 16 + lr] = f2bf(v1);
      }
  }
  __syncthreads();
  #pragma unroll
  for (int pass = 0; pass < 4; ++pass) {
    int p = (t >> 4) + pass*16;
    int c = (t & 15) * 8;
    *(bf16x8*)(kbf + (pixbase + p)*(size_t)CB + c) = *(bf16x8*)&As2[p*136 + c];
  }
  __syncthreads();
  {
    float bv0 = bv[n0+lr], bv1 = bv[n0+16+lr];
    #pragma unroll
    for (int mt = 0; mt < 4; ++mt)
      #pragma unroll
      for (int r = 0; r < 4; ++r) {
        int p = mt*16 + lg*4 + r;
        As2[p*136 + n0 + lr]      = f2bf(av[mt][0][r] + bv0);
        As2[p*136 + n0 + 16 + lr] = f2bf(av[mt][1][r] + bv1);
      }
  }
  __syncthreads();
  #pragma unroll
  for (int pass = 0; pass < 4; ++pass) {
    int p = (t >> 4) + pass*16;
    int c = (t & 15) * 8;
    *(bf16x8*)(vbf + (pixbase + p)*(size_t)CB + c) = *(bf16x8*)&As2[p*136 + c];
  }
}

// ---------------- per-window kmean (f32) + kv^T (bf16), bf16 inputs ----------------
template<int WS>
__global__ __launch_bounds__(256)
void k_winkv(const ushort* __restrict__ kall, const ushort* __restrict__ vall,
             float* __restrict__ km, ushort* __restrict__ kvT) {
  constexpr int NWIN = (HSW - WS)/(WS/2) + 1;
  constexpr int NK = WS*WS;
  __shared__ __align__(16) float kl[32][128];
  __shared__ __align__(16) float vl[32][128];
  int w = blockIdx.x;
  int b = w / (NWIN*NWIN);
  int rem = w - b*(NWIN*NWIN);
  int wi = rem / NWIN, wj = rem - (rem/NWIN)*NWIN;
  int y0 = wi*(WS/2), x0 = wj*(WS/2);
  int t = threadIdx.x;
  int h = t >> 6, d = (t>>1)&31, ep = t&1, e0 = ep*16;
  float acc[16];
  #pragma unroll
  for (int k2 = 0; k2 < 16; ++k2) acc[k2] = 0.f;
  float ksum = 0.f;
  for (int n0 = 0; n0 < NK; n0 += 32) {
    __syncthreads();
    #pragma unroll
    for (int e = t; e < 2048; e += 256) {
      int c2 = e & 63, rr = e >> 6;
      int n = n0 + rr;
      int py = y0 + n / WS, px = x0 + (n - (n/WS)*WS);
      size_t base = ((size_t)b*HSP + (size_t)py*HSW + px)*CB + c2*2;
      uint kw = *(const uint*)(kall + base);
      uint vw = *(const uint*)(vall + base);
      *(float2*)&kl[rr][c2*2] = make_float2(bf2f(kw & 0xffffu), bf2f(kw >> 16));
      *(float2*)&vl[rr][c2*2] = make_float2(bf2f(vw & 0xffffu), bf2f(vw >> 16));
    }
    __syncthreads();
    #pragma unroll 4
    for (int rr = 0; rr < 32; ++rr) {
      float kd = kl[rr][h*32+d];
      ksum += kd;
      #pragma unroll
      for (int k4 = 0; k4 < 4; ++k4) {
        float4 v4 = *(const float4*)&vl[rr][h*32+e0+k4*4];
        acc[k4*4+0] += kd*v4.x;
        acc[k4*4+1] += kd*v4.y;
        acc[k4*4+2] += kd*v4.z;
        acc[k4*4+3] += kd*v4.w;
      }
    }
  }
  ushort* kvp = kvT + (size_t)w*4096 + h*1024 + d;
  #pragma unroll
  for (int k2 = 0; k2 < 16; ++k2)
    kvp[(size_t)(e0+k2)*32] = f2bf(acc[k2] * (1.f/WS));
  if (ep == 0) km[(size_t)w*128 + h*32 + d] = ksum * (1.f/NK);
}

// ---- fused LN + q-proj + gather-fold + wo-GEMM + blend, per 8x8 tile ----
// smem_raw aliased: phase A = ushort As[64*136] (q / acc staging);
//                   phase B = float Cs[128*68]  (final C transpose).
__global__ __launch_bounds__(256)
void k_qfold(const float* __restrict__ low,
             const float* __restrict__ lng, const float* __restrict__ lnb,
             const ushort* __restrict__ wqb, const float* __restrict__ bq,
             const float* __restrict__ km8, const ushort* __restrict__ kv8T,
             const float* __restrict__ km16, const ushort* __restrict__ kv16T,
             const float* __restrict__ wwt,
             const ushort* __restrict__ wobf, const float* __restrict__ bo,
             const float* __restrict__ alpha,
             float* __restrict__ out0, float* __restrict__ out1) {
  __shared__ __align__(16) char smem_raw[128*68*4];   // 34816 B
  ushort* As = (ushort*)smem_raw;
  float* Cs = (float*)smem_raw;
  __shared__ float red[512];
  __shared__ float stat_m[64], stat_r[64];
  int t = threadIdx.x;
  // XCD chunk swizzle: 2048 blocks, 8 XCDs -> each XCD owns one batch image
  int bid = blockIdx.x;
  int swz = (bid & 7) * 256 + (bid >> 3);
  int bb = swz >> 8;
  int tile = swz & 255;
  int y0 = (tile >> 4) * 8, x0 = (tile & 15) * 8;

  int p = t & 63, cs = t >> 6;
  int ppy = p >> 3, ppx = p & 7;
  const float* xb = low + (size_t)bb*CB*LP + (size_t)(y0+ppy)*LW + (x0+ppx);
  float x[32];
  {
    float s = 0.f, ss = 0.f;
    #pragma unroll
    for (int j = 0; j < 32; ++j) {
      x[j] = xb[(size_t)(cs*32 + j)*LP];
      s += x[j]; ss += x[j]*x[j];
    }
    red[cs*64 + p] = s;
    red[256 + cs*64 + p] = ss;
  }
  __syncthreads();
  if (t < 64) {
    float s  = red[t] + red[64+t] + red[128+t] + red[192+t];
    float ss = red[256+t] + red[320+t] + red[384+t] + red[448+t];
    float m = s * (1.f/128.f);
    float var = ss * (1.f/128.f) - m*m;
    stat_m[t] = m;
    stat_r[t] = rsqrtf(fmaxf(var, 0.f) + 1e-5f);
  }
  __syncthreads();
  {
    float m = stat_m[p], r = stat_r[p];
    #pragma unroll
    for (int j8 = 0; j8 < 4; ++j8) {
      bf16x8 pk;
      #pragma unroll
      for (int jj = 0; jj < 8; ++jj) {
        int c = cs*32 + j8*8 + jj;
        pk[jj] = (short)f2bf((x[j8*8 + jj] - m)*r*lng[c] + lnb[c]);
      }
      *(bf16x8*)&As[p*136 + cs*32 + j8*8] = pk;
    }
  }
  __syncthreads();

  int l = t & 63, h = t >> 6;
  int lr = l & 15, lg = l >> 4;
  int n0 = h * 32;

  // q-GEMM
  f32x4 qa[4][2];
  #pragma unroll
  for (int mt = 0; mt < 4; ++mt)
    #pragma unroll
    for (int nt = 0; nt < 2; ++nt) qa[mt][nt] = (f32x4){0.f,0.f,0.f,0.f};
  #pragma unroll
  for (int k0 = 0; k0 < 128; k0 += 32) {
    bf16x8 a[4], bf[2];
    #pragma unroll
    for (int mt = 0; mt < 4; ++mt)
      a[mt] = *(bf16x8*)&As[(mt*16+lr)*136 + k0 + lg*8];
    #pragma unroll
    for (int nt = 0; nt < 2; ++nt)
      bf[nt] = *(const bf16x8*)(wqb + (size_t)(n0 + nt*16 + lr)*128 + k0 + lg*8);
    #pragma unroll
    for (int mt = 0; mt < 4; ++mt)
      #pragma unroll
      for (int nt = 0; nt < 2; ++nt)
        qa[mt][nt] = __builtin_amdgcn_mfma_f32_16x16x32_bf16(a[mt], bf[nt], qa[mt][nt], 0,0,0);
  }
  __syncthreads();
  // elu+1 epilogue -> As (q, bf16, pixel-major)
  {
    float b0 = bq[n0+lr], b1 = bq[n0+16+lr];
    #pragma unroll
    for (int mt = 0; mt < 4; ++mt)
      #pragma unroll
      for (int r = 0; r < 4; ++r) {
        int pp = mt*16 + lg*4 + r;
        float v0 = qa[mt][0][r] + b0;
        float v1 = qa[mt][1][r] + b1;
        v0 = (v0 > 0.f) ? v0 + 1.f : __expf(v0);
        v1 = (v1 > 0.f) ? v1 + 1.f : __expf(v1);
        As[pp*136 + n0 + lr]      = f2bf(v0);
        As[pp*136 + n0 + 16 + lr] = f2bf(v1);
      }
  }
  __syncthreads();

  // fold: A-frags from As (wave h reads its own head slab)
  bf16x8 aq[4];
  #pragma unroll
  for (int mt = 0; mt < 4; ++mt)
    aq[mt] = *(bf16x8*)&As[(mt*16+lr)*136 + h*32 + lg*8];

  float ww0 = wwt[0], ww1 = wwt[1];

  bf16x8 kmf = {0,0,0,0,0,0,0,0};
  {
    int s = lr;
    int wsi = (s >> 2) & 1;
    int n = wsi ? 7 : 15;
    int ar = (y0 >> (3+wsi)) - 1 + ((s>>1)&1);
    int ac = (x0 >> (3+wsi)) - 1 + (s&1);
    if (s < 8 && ar >= 0 && ar < n && ac >= 0 && ac < n) {
      size_t w = ((size_t)bb*n + ar)*n + ac;
      const float* kmp = (wsi ? km16 : km8) + w*(size_t)CB + h*32 + lg*8;
      #pragma unroll
      for (int j = 0; j < 8; ++j) kmf[j] = (short)f2bf(kmp[j]);
    }
  }
  f32x4 z4 = {0.f,0.f,0.f,0.f};
  f32x4 fm[4];
  #pragma unroll
  for (int mt = 0; mt < 4; ++mt) {
    f32x4 zf = __builtin_amdgcn_mfma_f32_16x16x32_bf16(aq[mt], kmf, z4, 0,0,0);
    float wwl = ((lr >> 2) & 1) ? ww1 : ww0;
    #pragma unroll
    for (int r = 0; r < 4; ++r) fm[mt][r] = wwl / (zf[r] + 1e-6f);
  }

  float acc0[4][4], acc1[4][4];
  #pragma unroll
  for (int mt = 0; mt < 4; ++mt)
    #pragma unroll
    for (int r = 0; r < 4; ++r) { acc0[mt][r] = 0.f; acc1[mt][r] = 0.f; }

  #pragma unroll
  for (int s = 0; s < 8; ++s) {
    const int wsi = s >> 2;
    const int n = wsi ? 7 : 15;
    int ar = (y0 >> (3+wsi)) - 1 + ((s>>1)&1);
    int ac = (x0 >> (3+wsi)) - 1 + (s&1);
    if (ar < 0 || ar >= n || ac < 0 || ac >= n) continue;  // block-uniform
    size_t w = ((size_t)bb*n + ar)*n + ac;
    const ushort* kvp = (wsi ? kv16T : kv8T) + w*4096 + h*1024 + lg*8;
    bf16x8 b0 = *(const bf16x8*)(kvp + (size_t)lr*32);
    bf16x8 b1 = *(const bf16x8*)(kvp + (size_t)(16+lr)*32);
    #pragma unroll
    for (int mt = 0; mt < 4; ++mt) {
      f32x4 pv0 = __builtin_amdgcn_mfma_f32_16x16x32_bf16(aq[mt], b0, z4, 0,0,0);
      f32x4 pv1 = __builtin_amdgcn_mfma_f32_16x16x32_bf16(aq[mt], b1, z4, 0,0,0);
      #pragma unroll
      for (int r = 0; r < 4; ++r) {
        float fv = __shfl(fm[mt][r], (l & 48) | s, 64);
        acc0[mt][r] += fv * pv0[r];
        acc1[mt][r] += fv * pv1[r];
      }
    }
  }
  __syncthreads();
  // fold acc -> As bf16 (pixel-major) [same rounding as old accbf path]
  #pragma unroll
  for (int mt = 0; mt < 4; ++mt)
    #pragma unroll
    for (int r = 0; r < 4; ++r) {
      int pp = mt*16 + lg*4 + r;
      As[pp*136 + n0 + lr]      = f2bf(acc0[mt][r]);
      As[pp*136 + n0 + 16 + lr] = f2bf(acc1[mt][r]);
    }
  __syncthreads();

  // wo-GEMM: C[p][o] = acc @ wo^T
  f32x4 oc[4][2];
  #pragma unroll
  for (int mt = 0; mt < 4; ++mt)
    #pragma unroll
    for (int nt = 0; nt < 2; ++nt) oc[mt][nt] = (f32x4){0.f,0.f,0.f,0.f};
  #pragma unroll
  for (int k0 = 0; k0 < 128; k0 += 32) {
    bf16x8 a[4], bf[2];
    #pragma unroll
    for (int mt = 0; mt < 4; ++mt)
      a[mt] = *(bf16x8*)&As[(mt*16+lr)*136 + k0 + lg*8];
    #pragma unroll
    for (int nt = 0; nt < 2; ++nt)
      bf[nt] = *(const bf16x8*)(wobf + (size_t)(n0 + nt*16 + lr)*128 + k0 + lg*8);
    #pragma unroll
    for (int mt = 0; mt < 4; ++mt)
      #pragma unroll
      for (int nt = 0; nt < 2; ++nt)
        oc[mt][nt] = __builtin_amdgcn_mfma_f32_16x16x32_bf16(a[mt], bf[nt], oc[mt][nt], 0,0,0);
  }
  __syncthreads();   // all As reads done before Cs overwrite (aliased)
  #pragma unroll
  for (int mt = 0; mt < 4; ++mt)
    #pragma unroll
    for (int nt = 0; nt < 2; ++nt) {
      int o = n0 + nt*16 + lr;
      #pragma unroll
      for (int r = 0; r < 4; ++r) {
        int row = mt*16 + lg*4 + r;
        Cs[o*68 + row] = oc[mt][nt][r];
      }
    }
  __syncthreads();

  // epilogue: out0 = 0.5*(C + bo*mult); out1 = a*out0 + (1-a)*low
  float aB = alpha[0];
  int p0 = (t & 15) * 4;             // pixel group: 4 consecutive (same tile row-half)
  int prow = p0 >> 3, pxo = p0 & 7;
  int py_g = y0 + prow;
  int cy8  = (py_g >= 8)  + (py_g <= 119);
  int cy16 = (py_g >= 16) + (py_g <= 111);
  float mult[4];
  #pragma unroll
  for (int i = 0; i < 4; ++i) {
    int px_g = x0 + pxo + i;
    int cx8  = (px_g >= 8)  + (px_g <= 119);
    int cx16 = (px_g >= 16) + (px_g <= 111);
    mult[i] = (float)(cy8*cx8 + cy16*cx16);
  }
  size_t rowaddr = (size_t)py_g*LW + x0 + pxo;
  #pragma unroll
  for (int pass = 0; pass < 8; ++pass) {
    int o = (t >> 4) + pass*16;
    float4 c4 = *(float4*)&Cs[o*68 + p0];
    float bov = bo[o];
    size_t addr = ((size_t)bb*CB + o)*LP + rowaddr;
    float4 lw = *(const float4*)(low + addr);   // L2-hot (read at LN stage)
    float g0 = 0.5f*(c4.x + bov*mult[0]);
    float g1 = 0.5f*(c4.y + bov*mult[1]);
    float g2 = 0.5f*(c4.z + bov*mult[2]);
    float g3 = 0.5f*(c4.w + bov*mult[3]);
    *(float4*)(out0 + addr) = make_float4(g0,g1,g2,g3);
    *(float4*)(out1 + addr) = make_float4(aB*g0 + (1.f-aB)*lw.x,
                                          aB*g1 + (1.f-aB)*lw.y,
                                          aB*g2 + (1.f-aB)*lw.z,
                                          aB*g3 + (1.f-aB)*lw.w);
  }
}

extern "C" void kernel_launch(void* const* d_in, const int* in_sizes, int n_in,
                              void* d_out, int out_size, void* d_ws, size_t ws_size,
                              hipStream_t stream) {
  const float* high  = (const float*)d_in[0];
  const float* low   = (const float*)d_in[1];
  const float* cw    = (const float*)d_in[2];
  const float* cb    = (const float*)d_in[3];
  const float* lng   = (const float*)d_in[4];
  const float* lnb   = (const float*)d_in[5];
  const float* wq    = (const float*)d_in[6];
  const float* bq    = (const float*)d_in[7];
  const float* wk    = (const float*)d_in[8];
  const float* bk    = (const float*)d_in[9];
  const float* wv    = (const float*)d_in[10];
  const float* bv    = (const float*)d_in[11];
  const float* wo    = (const float*)d_in[12];
  const float* bo    = (const float*)d_in[13];
  const float* wwt   = (const float*)d_in[14];
  const float* alpha = (const float*)d_in[15];

  float* ws   = (float*)d_ws;
  ushort* kbf = (ushort*)(ws + OFF_KBF);
  ushort* vbf = (ushort*)(ws + OFF_VBF);
  float* km8  = ws + OFF_KM8;
  ushort* kv8T  = (ushort*)(ws + OFF_KV8T);
  float* km16 = ws + OFF_KM16;
  ushort* kv16T = (ushort*)(ws + OFF_KV16T);
  ushort* wqb = (ushort*)(ws + OFF_WQB);
  ushort* wkb = (ushort*)(ws + OFF_WKB);
  ushort* wvb = (ushort*)(ws + OFF_WVB);
  ushort* wob = (ushort*)(ws + OFF_WOB);
  ushort* cwb = (ushort*)(ws + OFF_CWB);

  float* out0 = (float*)d_out;
  float* out1 = out0 + (size_t)NB*CB*LP;

  k_castw<<<dim3(16,5), 256, 0, stream>>>(wq, wk, wv, wo, cw, wqb, wkb, wvb, wob, cwb);
  k_convkv<<<512, 256, 0, stream>>>(high, cwb, cb, lng, lnb, wkb, bk, wvb, bv, kbf, vbf);
  k_winkv<8><<<1800, 256, 0, stream>>>(kbf, vbf, km8, kv8T);
  k_winkv<16><<<392, 256, 0, stream>>>(kbf, vbf, km16, kv16T);
  k_qfold<<<2048, 256, 0, stream>>>(low, lng, lnb, wqb, bq, km8, kv8T, km16, kv16T,
                                    wwt, wob, bo, alpha, out0, out1);
}